// Round 19
// baseline (753.452 us; speedup 1.0000x reference)
//
#include <hip/hip_runtime.h>
#include <math.h>

// ---------------- problem constants ----------------
#define C_    256
#define NTOK  65536   // B * 64 * 64

// LDS sizes (bytes)
#define AP_LDS   (4*64*72*2 + 64*256*2)     // 69,632
#define MLP2_LDS ((2*64*64 + 2*4*64*64)*2)  // 81,920 (outT overlays)

typedef __bf16 bf16x8 __attribute__((ext_vector_type(8)));
typedef float  f32x4  __attribute__((ext_vector_type(4)));
#define MFMA16(a,b,c) __builtin_amdgcn_mfma_f32_16x16x32_bf16((a),(b),(c),0,0,0)

__device__ inline ushort f2b(float f) {
    unsigned u = __builtin_bit_cast(unsigned, f);
    return (ushort)((u + 0x7fffu + ((u >> 16) & 1u)) >> 16);   // RNE
}

// fast gelu: x * sigmoid(1.59577x + 0.0713548x^3)
__device__ inline float fast_gelu(float x) {
    float u = 1.5957691216f * x + 0.0713548163f * x * x * x;
    return x * __builtin_amdgcn_rcpf(1.0f + __expf(-u));
}

union BF8u { ushort u[8]; bf16x8 v; };
__device__ inline bf16x8 cvt8(float4 a, float4 b) {
    BF8u t;
    t.u[0] = f2b(a.x); t.u[1] = f2b(a.y); t.u[2] = f2b(a.z); t.u[3] = f2b(a.w);
    t.u[4] = f2b(b.x); t.u[5] = f2b(b.y); t.u[6] = f2b(b.z); t.u[7] = f2b(b.w);
    return t.v;
}

// 16-MFMA tile update
#define TILE_MFMA(ACC, A, B)                                   \
    _Pragma("unroll") for (int mf_ = 0; mf_ < 4; ++mf_)        \
        _Pragma("unroll") for (int nf_ = 0; nf_ < 4; ++nf_)    \
            ACC[mf_][nf_] = MFMA16(A[mf_], B[nf_], ACC[mf_][nf_]);

// ---------------- f32 -> bf16 conversion (weights, tokens sidecar init) ----------------
__global__ void f2b_kernel(ushort* __restrict__ dst, const float* __restrict__ src) {
    size_t i = ((size_t)blockIdx.x * 256 + threadIdx.x) * 4;
    float4 v = *reinterpret_cast<const float4*>(src + i);
    ushort4 u = { f2b(v.x), f2b(v.y), f2b(v.z), f2b(v.w) };
    *reinterpret_cast<ushort4*>(dst + i) = u;
}

// ---------------- continuous position bias table ----------------
__global__ void cpb_kernel(const float* __restrict__ w1, const float* __restrict__ b1,
                           const float* __restrict__ w2, float* __restrict__ biastab) {
    __shared__ float red[256];
    const int e = blockIdx.x;
    const int t = threadIdx.x;
    const int p = e / 15, q = e % 15;
    const float v0 = (float)(p - 7) * (8.0f / 7.0f);
    const float v1 = (float)(q - 7) * (8.0f / 7.0f);
    const float t0 = copysignf(log2f(fabsf(v0) + 1.0f) * (1.0f / 3.0f), v0);
    const float t1 = copysignf(log2f(fabsf(v1) + 1.0f) * (1.0f / 3.0f), v1);
    const float ha = fmaxf(0.0f, t0 * w1[t * 2]         + t1 * w1[t * 2 + 1]         + b1[t]);
    const float hb = fmaxf(0.0f, t0 * w1[(t + 256) * 2] + t1 * w1[(t + 256) * 2 + 1] + b1[t + 256]);
    for (int h = 0; h < 8; ++h) {
        __syncthreads();
        red[t] = ha * w2[h * 512 + t] + hb * w2[h * 512 + t + 256];
        __syncthreads();
        for (int s = 128; s > 0; s >>= 1) {
            if (t < s) red[t] += red[t + s];
            __syncthreads();
        }
        if (t == 0) biastab[e * 8 + h] = 16.0f / (1.0f + expf(-red[0]));
    }
}

// ---------------- expand bias to [8][64][64] ----------------
__global__ void biasx_kernel(const float* __restrict__ biastab, float* __restrict__ biasx) {
    int h = blockIdx.x >> 6, n = blockIdx.x & 63, m = threadIdx.x;
    int idx = ((n >> 3) - (m >> 3) + 7) * 15 + ((n & 7) - (m & 7) + 7);
    biasx[((size_t)(h * 64 + n)) * 64 + m] = biastab[idx * 8 + h];
}

// ---------------- qkv GEMM: one block per (round, window); A from bf16 sidecar xb ----------------
__global__ __launch_bounds__(256, 3) void qkv_kernel(
    const ushort* __restrict__ xb, const ushort* __restrict__ qwb,
    const float* __restrict__ qb, ushort* __restrict__ q_ws,
    ushort* __restrict__ k_ws, ushort* __restrict__ vT_ws,
    int shift, int win0)
{
    __shared__ ushort xs[64 * 256];
    const int t = threadIdx.x;
    const int lwin = blockIdx.y, win = win0 + lwin;
    const int round = blockIdx.x;
    const int b = win >> 6, wh = (win >> 3) & 7, ww = win & 7;
    const int w = t >> 6, l = t & 63, lr = l & 15, lg = l >> 4;
    const int aswz = (lr & 7) << 3;
    const f32x4 zf = { 0.f, 0.f, 0.f, 0.f };

    {   // stage rolled window tokens: pure bf16 copy, swizzled
        int row = t >> 2, seg = t & 3;
        int i = row >> 3, j = row & 7;
        int rr = (wh * 8 + i + shift) & 63;
        int cc = (ww * 8 + j + shift) & 63;
        const ushort* src = xb + ((size_t)(b * 4096 + rr * 64 + cc)) * 256 + seg * 64;
        #pragma unroll
        for (int k8 = 0; k8 < 8; ++k8) {
            bf16x8 v = *reinterpret_cast<const bf16x8*>(src + k8 * 8);
            int col = seg * 64 + k8 * 8;
            *reinterpret_cast<bf16x8*>(xs + row * 256 + (col ^ ((row & 7) << 3))) = v;
        }
    }
    __syncthreads();

#define QK_LA(D, KT) { int k0_ = (KT) * 32 + lg * 8;                                        \
    _Pragma("unroll") for (int mf_ = 0; mf_ < 4; ++mf_)                                     \
        D[mf_] = *reinterpret_cast<const bf16x8*>(xs + (mf_ * 16 + lr) * 256 + (k0_ ^ aswz)); }
#define QK_LB(D, KT) { int k0_ = (KT) * 32 + lg * 8;                                        \
    _Pragma("unroll") for (int nf_ = 0; nf_ < 4; ++nf_)                                     \
        D[nf_] = *reinterpret_cast<const bf16x8*>(qwb + (size_t)(colb + nf_ * 16 + lr) * 256 + k0_); }

    const int colb = round * 256 + w * 64;
    f32x4 acc[4][4];
    #pragma unroll
    for (int mf = 0; mf < 4; ++mf)
        #pragma unroll
        for (int nf = 0; nf < 4; ++nf) acc[mf][nf] = zf;

    bf16x8 pb[3][4];
    QK_LB(pb[0], 0); QK_LB(pb[1], 1);
    #pragma unroll
    for (int kt = 0; kt < 8; ++kt) {
        if (kt + 2 < 8) QK_LB(pb[(kt + 2) % 3], kt + 2);
        bf16x8 pa[4];
        QK_LA(pa, kt);
        TILE_MFMA(acc, pa, pb[kt % 3]);
    }

    // bias add
    #pragma unroll
    for (int nf = 0; nf < 4; ++nf) {
        float bb = qb[colb + nf * 16 + lr];
        #pragma unroll
        for (int mf = 0; mf < 4; ++mf)
            #pragma unroll
            for (int r = 0; r < 4; ++r) acc[mf][nf][r] += bb;
    }

    if (round < 2) {
        float ss0[4][4], ss1[4][4];
        #pragma unroll
        for (int mf = 0; mf < 4; ++mf)
            #pragma unroll
            for (int r = 0; r < 4; ++r) {
                ss0[mf][r] = acc[mf][0][r] * acc[mf][0][r] + acc[mf][1][r] * acc[mf][1][r];
                ss1[mf][r] = acc[mf][2][r] * acc[mf][2][r] + acc[mf][3][r] * acc[mf][3][r];
            }
        #pragma unroll
        for (int m = 1; m < 16; m <<= 1)
            #pragma unroll
            for (int mf = 0; mf < 4; ++mf)
                #pragma unroll
                for (int r = 0; r < 4; ++r) {
                    ss0[mf][r] += __shfl_xor(ss0[mf][r], m);
                    ss1[mf][r] += __shfl_xor(ss1[mf][r], m);
                }
        ushort* dst = (round == 0) ? q_ws : k_ws;
        #pragma unroll
        for (int mf = 0; mf < 4; ++mf)
            #pragma unroll
            for (int r = 0; r < 4; ++r) {
                float rs0 = 1.0f / (sqrtf(ss0[mf][r]) + 1e-12f);
                float rs1 = 1.0f / (sqrtf(ss1[mf][r]) + 1e-12f);
                size_t rowoff = ((size_t)lwin * 64 + mf * 16 + lg * 4 + r) * 256;
                #pragma unroll
                for (int nf = 0; nf < 4; ++nf)
                    dst[rowoff + w * 64 + nf * 16 + lr] =
                        f2b(acc[mf][nf][r] * (nf < 2 ? rs0 : rs1));
            }
    } else {
        #pragma unroll
        for (int nf = 0; nf < 4; ++nf) {
            int h = 2 * w + (nf >> 1);
            int chan = (nf & 1) * 16 + lr;
            ushort* vrow = vT_ws + (((size_t)lwin * 8 + h) * 32 + chan) * 64;
            #pragma unroll
            for (int mf = 0; mf < 4; ++mf)
                #pragma unroll
                for (int r = 0; r < 4; ++r)
                    vrow[mf * 16 + lg * 4 + r] = f2b(acc[mf][nf][r]);
        }
    }
#undef QK_LA
#undef QK_LB
}

// ---------------- fused attention (S+softmax+PV) + proj + post-LN + residual ----------------
// epilogue maintains bf16 sidecar xbo alongside f32 xout
__global__ __launch_bounds__(256, 2) void attnproj_kernel(
    const ushort* __restrict__ q_ws, const ushort* __restrict__ k_ws,
    const ushort* __restrict__ vT_ws, const ushort* __restrict__ pwb,
    const float* __restrict__ pb, const float* __restrict__ lsc,
    const float* __restrict__ biasx, const float* __restrict__ n1s,
    const float* __restrict__ n1b, const float* __restrict__ xin,
    float* __restrict__ xout, ushort* __restrict__ xbo, int shift, int win0)
{
    extern __shared__ ushort sm[];
    ushort* aol  = sm + 4 * 64 * 72;    // [64][256] bf16, swizzled
    float*  outT = (float*)sm;          // [64][264] f32 overlay

    const int t = threadIdx.x;
    const int win = win0 + blockIdx.x, lwin = blockIdx.x;
    const int b = win >> 6, wh = (win >> 3) & 7, ww = win & 7;
    const int w = t >> 6, l = t & 63, lr = l & 15, lg = l >> 4;
    ushort* Pw = sm + w * 64 * 72;      // wave-private P
    const size_t tokbase = (size_t)lwin * 64;
    const f32x4 zf = { 0.f, 0.f, 0.f, 0.f };

    int regc[4], regr[4][4];
    #pragma unroll
    for (int nf = 0; nf < 4; ++nf) {
        int kc = nf * 16 + lr;
        int pr = wh * 8 + (kc >> 3), pc = ww * 8 + (kc & 7);
        regc[nf] = ((pr < 56) ? 0 : ((pr < 60) ? 1 : 2)) * 3 +
                   ((pc < 56) ? 0 : ((pc < 60) ? 1 : 2));
    }
    #pragma unroll
    for (int mf = 0; mf < 4; ++mf)
        #pragma unroll
        for (int r = 0; r < 4; ++r) {
            int n = mf * 16 + lg * 4 + r;
            int pr = wh * 8 + (n >> 3), pc = ww * 8 + (n & 7);
            regr[mf][r] = ((pr < 56) ? 0 : ((pr < 60) ? 1 : 2)) * 3 +
                          ((pc < 56) ? 0 : ((pc < 60) ? 1 : 2));
        }

    for (int hr = 0; hr < 2; ++hr) {
        const int h = w * 2 + hr;

        f32x4 sacc[4][4];
        {
            bf16x8 aq[4], bk[4];
            #pragma unroll
            for (int mf = 0; mf < 4; ++mf)
                aq[mf] = *reinterpret_cast<const bf16x8*>(
                    q_ws + (tokbase + mf * 16 + lr) * 256 + h * 32 + lg * 8);
            #pragma unroll
            for (int nf = 0; nf < 4; ++nf)
                bk[nf] = *reinterpret_cast<const bf16x8*>(
                    k_ws + (tokbase + nf * 16 + lr) * 256 + h * 32 + lg * 8);
            #pragma unroll
            for (int mf = 0; mf < 4; ++mf)
                #pragma unroll
                for (int nf = 0; nf < 4; ++nf)
                    sacc[mf][nf] = MFMA16(aq[mf], bk[nf], zf);
        }

        const float scale = __expf(fminf(lsc[h], 4.6051702f));
        float mx[4][4], sum[4][4];
        #pragma unroll
        for (int mf = 0; mf < 4; ++mf)
            #pragma unroll
            for (int r = 0; r < 4; ++r) mx[mf][r] = -1e30f;

        #pragma unroll
        for (int nf = 0; nf < 4; ++nf)
            #pragma unroll
            for (int mf = 0; mf < 4; ++mf)
                #pragma unroll
                for (int r = 0; r < 4; ++r) {
                    float v = sacc[mf][nf][r] * scale +
                              biasx[((size_t)(h * 64 + mf * 16 + lg * 4 + r)) * 64 + nf * 16 + lr];
                    if (shift && regc[nf] != regr[mf][r]) v -= 100.0f;
                    sacc[mf][nf][r] = v;
                    mx[mf][r] = fmaxf(mx[mf][r], v);
                }
        #pragma unroll
        for (int m = 1; m < 16; m <<= 1)
            #pragma unroll
            for (int mf = 0; mf < 4; ++mf)
                #pragma unroll
                for (int r = 0; r < 4; ++r) mx[mf][r] = fmaxf(mx[mf][r], __shfl_xor(mx[mf][r], m));

        #pragma unroll
        for (int mf = 0; mf < 4; ++mf)
            #pragma unroll
            for (int r = 0; r < 4; ++r) sum[mf][r] = 0.f;
        #pragma unroll
        for (int nf = 0; nf < 4; ++nf)
            #pragma unroll
            for (int mf = 0; mf < 4; ++mf)
                #pragma unroll
                for (int r = 0; r < 4; ++r) {
                    float e = __expf(sacc[mf][nf][r] - mx[mf][r]);
                    sacc[mf][nf][r] = e;
                    sum[mf][r] += e;
                }
        #pragma unroll
        for (int m = 1; m < 16; m <<= 1)
            #pragma unroll
            for (int mf = 0; mf < 4; ++mf)
                #pragma unroll
                for (int r = 0; r < 4; ++r) sum[mf][r] += __shfl_xor(sum[mf][r], m);

        #pragma unroll
        for (int nf = 0; nf < 4; ++nf)
            #pragma unroll
            for (int mf = 0; mf < 4; ++mf)
                #pragma unroll
                for (int r = 0; r < 4; ++r)
                    Pw[(mf * 16 + lg * 4 + r) * 72 + nf * 16 + lr] = f2b(sacc[mf][nf][r]);

        f32x4 oacc[4][2];
        #pragma unroll
        for (int mf = 0; mf < 4; ++mf)
            #pragma unroll
            for (int nf = 0; nf < 2; ++nf) oacc[mf][nf] = zf;
        #pragma unroll
        for (int ks = 0; ks < 2; ++ks) {
            bf16x8 pa[4], bv[2];
            #pragma unroll
            for (int mf = 0; mf < 4; ++mf)
                pa[mf] = *reinterpret_cast<const bf16x8*>(Pw + (mf * 16 + lr) * 72 + ks * 32 + lg * 8);
            #pragma unroll
            for (int nf = 0; nf < 2; ++nf)
                bv[nf] = *reinterpret_cast<const bf16x8*>(
                    vT_ws + (((size_t)lwin * 8 + h) * 32 + nf * 16 + lr) * 64 + ks * 32 + lg * 8);
            #pragma unroll
            for (int mf = 0; mf < 4; ++mf)
                #pragma unroll
                for (int nf = 0; nf < 2; ++nf)
                    oacc[mf][nf] = MFMA16(pa[mf], bv[nf], oacc[mf][nf]);
        }

        #pragma unroll
        for (int mf = 0; mf < 4; ++mf)
            #pragma unroll
            for (int r = 0; r < 4; ++r) {
                float inv = 1.0f / sum[mf][r];
                int row = mf * 16 + lg * 4 + r;
                #pragma unroll
                for (int nf = 0; nf < 2; ++nf) {
                    int col = h * 32 + nf * 16 + lr;
                    aol[row * 256 + (col ^ ((row & 7) << 3))] = f2b(oacc[mf][nf][r] * inv);
                }
            }
    }
    __syncthreads();

    // ---- proj GEMM: M=64, N=64 (wave slice), K=256, prefetched ----
    const int aswz = (lr & 7) << 3;
#define PJ_LA(D, KT) { int k0_ = (KT) * 32 + lg * 8;                                          \
    _Pragma("unroll") for (int mf_ = 0; mf_ < 4; ++mf_)                                       \
        D[mf_] = *reinterpret_cast<const bf16x8*>(aol + (mf_ * 16 + lr) * 256 + (k0_ ^ aswz)); }
#define PJ_LB(D, KT) { int k0_ = (KT) * 32 + lg * 8;                                          \
    _Pragma("unroll") for (int nf_ = 0; nf_ < 4; ++nf_)                                       \
        D[nf_] = *reinterpret_cast<const bf16x8*>(pwb + (size_t)(w * 64 + nf_ * 16 + lr) * 256 + k0_); }

    f32x4 acc[4][4];
    #pragma unroll
    for (int mf = 0; mf < 4; ++mf)
        #pragma unroll
        for (int nf = 0; nf < 4; ++nf) acc[mf][nf] = zf;
    {
        bf16x8 pa0[4], pb0[4], pa1[4], pb1[4];
        PJ_LA(pa0, 0); PJ_LB(pb0, 0);
        #pragma unroll
        for (int kt = 0; kt < 8; kt += 2) {
            PJ_LA(pa1, kt + 1); PJ_LB(pb1, kt + 1);
            TILE_MFMA(acc, pa0, pb0);
            if (kt + 2 < 8) { PJ_LA(pa0, kt + 2); PJ_LB(pb0, kt + 2); }
            TILE_MFMA(acc, pa1, pb1);
        }
    }
#undef PJ_LA
#undef PJ_LB
    __syncthreads();

    #pragma unroll
    for (int nf = 0; nf < 4; ++nf) {
        int c = w * 64 + nf * 16 + lr;
        float bb = pb[c];
        #pragma unroll
        for (int mf = 0; mf < 4; ++mf)
            #pragma unroll
            for (int r = 0; r < 4; ++r)
                outT[(mf * 16 + lg * 4 + r) * 264 + c] = acc[mf][nf][r] + bb;
    }
    __syncthreads();

    for (int u = 0; u < 16; ++u) {
        int tk = w * 16 + u;
        float v0 = outT[tk * 264 + l];
        float v1 = outT[tk * 264 + l + 64];
        float v2 = outT[tk * 264 + l + 128];
        float v3 = outT[tk * 264 + l + 192];
        float s = v0 + v1 + v2 + v3, ss = v0 * v0 + v1 * v1 + v2 * v2 + v3 * v3;
        for (int m = 1; m < 64; m <<= 1) { s += __shfl_xor(s, m); ss += __shfl_xor(ss, m); }
        float mean = s * (1.0f / 256.0f);
        float var  = ss * (1.0f / 256.0f) - mean * mean;
        float rs   = rsqrtf(var + 1e-5f);

        int i = tk >> 3, j = tk & 7;
        int pr = (wh * 8 + i + shift) & 63;
        int pc = (ww * 8 + j + shift) & 63;
        size_t gaddr = ((size_t)(b * 4096 + pr * 64 + pc)) * 256;
        float o0 = xin[gaddr + l]       + (v0 - mean) * rs * n1s[l]       + n1b[l];
        float o1 = xin[gaddr + l + 64]  + (v1 - mean) * rs * n1s[l + 64]  + n1b[l + 64];
        float o2 = xin[gaddr + l + 128] + (v2 - mean) * rs * n1s[l + 128] + n1b[l + 128];
        float o3 = xin[gaddr + l + 192] + (v3 - mean) * rs * n1s[l + 192] + n1b[l + 192];
        xout[gaddr + l]       = o0;  xbo[gaddr + l]       = f2b(o0);
        xout[gaddr + l + 64]  = o1;  xbo[gaddr + l + 64]  = f2b(o1);
        xout[gaddr + l + 128] = o2;  xbo[gaddr + l + 128] = f2b(o2);
        xout[gaddr + l + 192] = o3;  xbo[gaddr + l + 192] = f2b(o3);
    }
}

// ---------------- MLP GEMM1: hid = fast_gelu(xb @ w1^T + b1) -> hidb (bf16, chunk-local) ----------------
__global__ __launch_bounds__(256, 2) void mlp1_kernel(
    const ushort* __restrict__ xb, const ushort* __restrict__ w1b,
    const float* __restrict__ b1, ushort* __restrict__ hidb, int tok_base)
{
    __shared__ ushort xs[64 * 256];      // 32 KB
    __shared__ ushort hstage[64 * 256];  // 32 KB
    const int t = threadIdx.x;
    const size_t ltok0 = (size_t)blockIdx.x * 64;
    const size_t tok0  = (size_t)tok_base + ltok0;
    const int w = t >> 6, l = t & 63, lr = l & 15, lg = l >> 4;
    const int aswz = (lr & 7) << 3;
    const f32x4 zf = { 0.f, 0.f, 0.f, 0.f };

    {   // stage x tile: pure bf16 copy, swizzled
        int row = t >> 2, seg = t & 3;
        const ushort* src = xb + (tok0 + row) * 256 + seg * 64;
        #pragma unroll
        for (int k8 = 0; k8 < 8; ++k8) {
            bf16x8 v = *reinterpret_cast<const bf16x8*>(src + k8 * 8);
            int col = seg * 64 + k8 * 8;
            *reinterpret_cast<bf16x8*>(xs + row * 256 + (col ^ ((row & 7) << 3))) = v;
        }
    }
    __syncthreads();

#define M1_LA(D, KT) { int k0_ = (KT) * 32 + lg * 8;                                        \
    _Pragma("unroll") for (int mf_ = 0; mf_ < 4; ++mf_)                                     \
        D[mf_] = *reinterpret_cast<const bf16x8*>(xs + (mf_ * 16 + lr) * 256 + (k0_ ^ aswz)); }
#define M1_LB(D, KT) { int k0_ = (KT) * 32 + lg * 8;                                        \
    _Pragma("unroll") for (int nf_ = 0; nf_ < 4; ++nf_)                                     \
        D[nf_] = *reinterpret_cast<const bf16x8*>(w1b + (size_t)(n0 + nf_ * 16 + lr) * 256 + k0_); }

    for (int q = 0; q < 4; ++q) {
        const int n0 = q * 256 + w * 64;
        f32x4 acc[4][4];
        #pragma unroll
        for (int mf = 0; mf < 4; ++mf)
            #pragma unroll
            for (int nf = 0; nf < 4; ++nf) acc[mf][nf] = zf;

        bf16x8 pb[3][4];
        M1_LB(pb[0], 0); M1_LB(pb[1], 1);
        #pragma unroll
        for (int kt = 0; kt < 8; ++kt) {
            if (kt + 2 < 8) M1_LB(pb[(kt + 2) % 3], kt + 2);
            bf16x8 pa[4];
            M1_LA(pa, kt);
            TILE_MFMA(acc, pa, pb[kt % 3]);
        }

        if (q > 0) __syncthreads();

        #pragma unroll
        for (int nf = 0; nf < 4; ++nf) {
            int lcol = w * 64 + nf * 16 + lr;
            float bb = b1[q * 256 + lcol];
            #pragma unroll
            for (int mf = 0; mf < 4; ++mf)
                #pragma unroll
                for (int r = 0; r < 4; ++r)
                    hstage[(mf * 16 + lg * 4 + r) * 256 + lcol] =
                        f2b(fast_gelu(acc[mf][nf][r] + bb));
        }
        __syncthreads();

        #pragma unroll
        for (int j = 0; j < 8; ++j) {
            int c = j * 256 + t;
            int row = c >> 5, cc = (c & 31) * 8;
            *reinterpret_cast<bf16x8*>(hidb + (ltok0 + row) * 1024 + q * 256 + cc) =
                *reinterpret_cast<const bf16x8*>(hstage + row * 256 + cc);
        }
    }
#undef M1_LA
#undef M1_LB
}

// ---------------- MLP GEMM2 (LDS-staged dbuf): out = hid @ w2^T + b2, post-LN, residual ----------------
// epilogue maintains bf16 sidecar xb alongside f32 x
__global__ __launch_bounds__(256, 2) void mlp2_kernel(
    const ushort* __restrict__ hidb, const ushort* __restrict__ w2b,
    const float* __restrict__ b2, const float* __restrict__ n2s,
    const float* __restrict__ n2b, float* __restrict__ x,
    ushort* __restrict__ xb, int tok_base)
{
    extern __shared__ ushort sm3[];
    ushort* As = sm3;                   // [2][64][64]
    ushort* Bs = sm3 + 2 * 64 * 64;     // [2][4][64][64]
    float*  outT = (float*)sm3;         // [64][264] overlay (epilogue)

    const int t = threadIdx.x;
    const size_t ltok0 = (size_t)blockIdx.x * 64;
    const size_t tok0  = (size_t)tok_base + ltok0;
    const int w = t >> 6, l = t & 63, lr = l & 15, lg = l >> 4;
    const f32x4 zf = { 0.f, 0.f, 0.f, 0.f };

    const int arow = t >> 2, aslot0 = (t & 3) * 2;
    const ushort* agp = hidb + (ltok0 + arow) * 1024;
    const ushort* bgp = w2b + (size_t)(w * 64 + l) * 1024;

    bf16x8 areg[2], breg[8];
    #pragma unroll
    for (int i = 0; i < 2; ++i)
        areg[i] = *reinterpret_cast<const bf16x8*>(agp + (aslot0 + i) * 8);
    #pragma unroll
    for (int s = 0; s < 8; ++s)
        breg[s] = *reinterpret_cast<const bf16x8*>(bgp + s * 8);
    {
        ushort* aw = As + arow * 64;
        ushort* bw = Bs + (size_t)(w * 64 + l) * 64;
        #pragma unroll
        for (int i = 0; i < 2; ++i)
            *reinterpret_cast<bf16x8*>(aw + (((aslot0 + i) ^ (arow & 7)) * 8)) = areg[i];
        #pragma unroll
        for (int s = 0; s < 8; ++s)
            *reinterpret_cast<bf16x8*>(bw + ((s ^ (l & 7)) * 8)) = breg[s];
    }

    f32x4 acc[4][4];
    #pragma unroll
    for (int mf = 0; mf < 4; ++mf)
        #pragma unroll
        for (int nf = 0; nf < 4; ++nf) acc[mf][nf] = zf;

    for (int kt = 0; kt < 16; ++kt) {
        const int cur = kt & 1, nxt = cur ^ 1;
        if (kt + 1 < 16) {
            #pragma unroll
            for (int i = 0; i < 2; ++i)
                areg[i] = *reinterpret_cast<const bf16x8*>(agp + (kt + 1) * 64 + (aslot0 + i) * 8);
            #pragma unroll
            for (int s = 0; s < 8; ++s)
                breg[s] = *reinterpret_cast<const bf16x8*>(bgp + (kt + 1) * 64 + s * 8);
        }
        __syncthreads();

        const ushort* ar = As + cur * 64 * 64;
        const ushort* br = Bs + (size_t)(cur * 4 + w) * 64 * 64;
        #pragma unroll
        for (int k2 = 0; k2 < 2; ++k2) {
            bf16x8 a[4], b[4];
            #pragma unroll
            for (int mf = 0; mf < 4; ++mf)
                a[mf] = *reinterpret_cast<const bf16x8*>(
                    ar + (mf * 16 + lr) * 64 + (((k2 * 4 + lg) ^ (lr & 7)) * 8));
            #pragma unroll
            for (int nf = 0; nf < 4; ++nf)
                b[nf] = *reinterpret_cast<const bf16x8*>(
                    br + (nf * 16 + lr) * 64 + (((k2 * 4 + lg) ^ (lr & 7)) * 8));
            TILE_MFMA(acc, a, b);
        }
        __syncthreads();

        if (kt + 1 < 16) {
            ushort* aw = As + nxt * 64 * 64 + arow * 64;
            ushort* bw = Bs + (size_t)(nxt * 4 + w) * 64 * 64 + (size_t)l * 64;
            #pragma unroll
            for (int i = 0; i < 2; ++i)
                *reinterpret_cast<bf16x8*>(aw + (((aslot0 + i) ^ (arow & 7)) * 8)) = areg[i];
            #pragma unroll
            for (int s = 0; s < 8; ++s)
                *reinterpret_cast<bf16x8*>(bw + ((s ^ (l & 7)) * 8)) = breg[s];
        }
    }
    __syncthreads();

    #pragma unroll
    for (int nf = 0; nf < 4; ++nf) {
        int c = w * 64 + nf * 16 + lr;
        float bb = b2[c];
        #pragma unroll
        for (int mf = 0; mf < 4; ++mf)
            #pragma unroll
            for (int r = 0; r < 4; ++r)
                outT[(mf * 16 + lg * 4 + r) * 264 + c] = acc[mf][nf][r] + bb;
    }
    __syncthreads();

    for (int u = 0; u < 16; ++u) {
        int tk = w * 16 + u;
        float v0 = outT[tk * 264 + l];
        float v1 = outT[tk * 264 + l + 64];
        float v2 = outT[tk * 264 + l + 128];
        float v3 = outT[tk * 264 + l + 192];
        float s = v0 + v1 + v2 + v3, ss = v0 * v0 + v1 * v1 + v2 * v2 + v3 * v3;
        for (int m = 1; m < 64; m <<= 1) { s += __shfl_xor(s, m); ss += __shfl_xor(ss, m); }
        float mean = s * (1.0f / 256.0f);
        float var  = ss * (1.0f / 256.0f) - mean * mean;
        float rs   = rsqrtf(var + 1e-5f);
        float* xp = x + (tok0 + tk) * 256;
        ushort* xbp = xb + (tok0 + tk) * 256;
        float o0 = xp[l]       + (v0 - mean) * rs * n2s[l]       + n2b[l];
        float o1 = xp[l + 64]  + (v1 - mean) * rs * n2s[l + 64]  + n2b[l + 64];
        float o2 = xp[l + 128] + (v2 - mean) * rs * n2s[l + 128] + n2b[l + 128];
        float o3 = xp[l + 192] + (v3 - mean) * rs * n2s[l + 192] + n2b[l + 192];
        xp[l]       = o0;  xbp[l]       = f2b(o0);
        xp[l + 64]  = o1;  xbp[l + 64]  = f2b(o1);
        xp[l + 128] = o2;  xbp[l + 128] = f2b(o2);
        xp[l + 192] = o3;  xbp[l + 192] = f2b(o3);
    }
}

// ---------------- launcher ----------------
extern "C" void kernel_launch(void* const* d_in, const int* in_sizes, int n_in,
                              void* d_out, int out_size, void* d_ws, size_t ws_size,
                              hipStream_t stream) {
    (void)in_sizes; (void)n_in; (void)out_size;
    const float* tokens = (const float*)d_in[0];
    const float* qkv_w  = (const float*)d_in[3];
    const float* qkv_b  = (const float*)d_in[4];
    const float* lsc    = (const float*)d_in[5];
    const float* cw1    = (const float*)d_in[6];
    const float* cb1    = (const float*)d_in[7];
    const float* cw2    = (const float*)d_in[8];
    const float* pw     = (const float*)d_in[9];
    const float* pb     = (const float*)d_in[10];
    const float* n1s    = (const float*)d_in[11];
    const float* n1b    = (const float*)d_in[12];
    const float* mw1    = (const float*)d_in[13];
    const float* mb1    = (const float*)d_in[14];
    const float* mw2    = (const float*)d_in[15];
    const float* mb2    = (const float*)d_in[16];
    const float* n2s    = (const float*)d_in[17];
    const float* n2b    = (const float*)d_in[18];

    float* x = (float*)d_out;

    // ---- workspace: weights | xb (32 MB bf16 sidecar) | q/k/vT (hidb overlays q/k/vT) ----
    ushort* pwb   = (ushort*)d_ws;                       // 256 KB
    ushort* w1b   = pwb + 2 * 256 * 256;                 // 1 MB
    ushort* w2b   = w1b + 2 * 1024 * 256;                // 1 MB
    ushort* qwb   = w2b + 2 * 256 * 1024;                // 768 KB
    float*  biasx = (float*)(qwb + 2 * 768 * 256);       // 128 KB
    float*  biastab = biasx + 8 * 64 * 64;               // 1800 f32
    char*   big   = (char*)d_ws + 3407872;               // 3.25 MB offset

    ushort* xb    = (ushort*)big;                        // NTOK*256 bf16 = 32 MB
    char*   big2  = big + (size_t)NTOK * 256 * 2;

    size_t avail2 = ws_size - 3407872 - (size_t)NTOK * 256 * 2;
    // window batching: all 1024 windows if q/k/vT (96 MB) fits after xb, else halves (48 MB)
    const int hwin = (avail2 >= (size_t)3 * 1024 * 64 * 256 * 2) ? 1024 : 512;
    const int chunk_tok = (avail2 >= (size_t)32768 * 2048) ? 32768 : 16384;

    ushort* q_ws  = (ushort*)big2;
    ushort* k_ws  = q_ws + (size_t)hwin * 64 * 256;
    ushort* vT_ws = k_ws + (size_t)hwin * 64 * 256;
    ushort* hidb  = (ushort*)big2;   // overlay (q/k/vT dead during MLP; xb stays live)

    f2b_kernel<<<dim3(2 * 256 * 256 / 1024),  dim3(256), 0, stream>>>(pwb, pw);
    f2b_kernel<<<dim3(2 * 1024 * 256 / 1024), dim3(256), 0, stream>>>(w1b, mw1);
    f2b_kernel<<<dim3(2 * 256 * 1024 / 1024), dim3(256), 0, stream>>>(w2b, mw2);
    f2b_kernel<<<dim3(2 * 768 * 256 / 1024),  dim3(256), 0, stream>>>(qwb, qkv_w);
    f2b_kernel<<<dim3(NTOK * 256 / 1024),     dim3(256), 0, stream>>>(xb, tokens);  // sidecar init

    for (int l = 0; l < 2; ++l) {
        const int shift = l ? 4 : 0;
        const float* xsrc = (l == 0) ? tokens : x;   // f32 residual source
        cpb_kernel<<<dim3(225), dim3(256), 0, stream>>>(
            cw1 + (size_t)l * 1024, cb1 + (size_t)l * 512, cw2 + (size_t)l * 4096, biastab);
        biasx_kernel<<<dim3(512), dim3(64), 0, stream>>>(biastab, biasx);
        for (int win0 = 0; win0 < 1024; win0 += hwin) {
            qkv_kernel<<<dim3(3, hwin), dim3(256), 0, stream>>>(
                xb, qwb + (size_t)l * 196608, qkv_b + (size_t)l * 768,
                q_ws, k_ws, vT_ws, shift, win0);
            attnproj_kernel<<<dim3(hwin), dim3(256), AP_LDS, stream>>>(
                q_ws, k_ws, vT_ws, pwb + (size_t)l * 65536, pb + (size_t)l * 256,
                lsc + (size_t)l * 8, biasx, n1s + (size_t)l * 256, n1b + (size_t)l * 256,
                xsrc, x, xb, shift, win0);
        }
        for (int tb = 0; tb < NTOK; tb += chunk_tok) {
            mlp1_kernel<<<dim3(chunk_tok / 64), dim3(256), 0, stream>>>(
                xb, w1b + (size_t)l * 262144, mb1 + (size_t)l * 1024, hidb, tb);
            mlp2_kernel<<<dim3(chunk_tok / 64), dim3(256), MLP2_LDS, stream>>>(
                hidb, w2b + (size_t)l * 262144, mb2 + (size_t)l * 256,
                n2s + (size_t)l * 256, n2b + (size_t)l * 256, x, xb, tb);
        }
    }
}

// Round 20
// 750.151 us; speedup vs baseline: 1.0044x; 1.0044x over previous
//
#include <hip/hip_runtime.h>
#include <math.h>

// ---------------- problem constants ----------------
#define C_    256
#define NTOK  65536   // B * 64 * 64

// LDS sizes (bytes)
#define AP_LDS   (4*64*72*2 + 64*256*2)     // 69,632
#define MLP2_LDS ((2*64*64 + 2*4*64*64)*2)  // 81,920 (outT overlays)

typedef __bf16 bf16x8 __attribute__((ext_vector_type(8)));
typedef float  f32x4  __attribute__((ext_vector_type(4)));
#define MFMA16(a,b,c) __builtin_amdgcn_mfma_f32_16x16x32_bf16((a),(b),(c),0,0,0)

__device__ inline ushort f2b(float f) {
    unsigned u = __builtin_bit_cast(unsigned, f);
    return (ushort)((u + 0x7fffu + ((u >> 16) & 1u)) >> 16);   // RNE
}

// fast gelu: x * sigmoid(1.59577x + 0.0713548x^3)
__device__ inline float fast_gelu(float x) {
    float u = 1.5957691216f * x + 0.0713548163f * x * x * x;
    return x * __builtin_amdgcn_rcpf(1.0f + __expf(-u));
}

union BF8u { ushort u[8]; bf16x8 v; };
__device__ inline bf16x8 cvt8(float4 a, float4 b) {
    BF8u t;
    t.u[0] = f2b(a.x); t.u[1] = f2b(a.y); t.u[2] = f2b(a.z); t.u[3] = f2b(a.w);
    t.u[4] = f2b(b.x); t.u[5] = f2b(b.y); t.u[6] = f2b(b.z); t.u[7] = f2b(b.w);
    return t.v;
}

// 16-MFMA tile update
#define TILE_MFMA(ACC, A, B)                                   \
    _Pragma("unroll") for (int mf_ = 0; mf_ < 4; ++mf_)        \
        _Pragma("unroll") for (int nf_ = 0; nf_ < 4; ++nf_)    \
            ACC[mf_][nf_] = MFMA16(A[mf_], B[nf_], ACC[mf_][nf_]);

// ---------------- f32 -> bf16 conversion (weights, tokens sidecar init) ----------------
__global__ void f2b_kernel(ushort* __restrict__ dst, const float* __restrict__ src) {
    size_t i = ((size_t)blockIdx.x * 256 + threadIdx.x) * 4;
    float4 v = *reinterpret_cast<const float4*>(src + i);
    ushort4 u = { f2b(v.x), f2b(v.y), f2b(v.z), f2b(v.w) };
    *reinterpret_cast<ushort4*>(dst + i) = u;
}

// ---------------- continuous position bias table ----------------
__global__ void cpb_kernel(const float* __restrict__ w1, const float* __restrict__ b1,
                           const float* __restrict__ w2, float* __restrict__ biastab) {
    __shared__ float red[256];
    const int e = blockIdx.x;
    const int t = threadIdx.x;
    const int p = e / 15, q = e % 15;
    const float v0 = (float)(p - 7) * (8.0f / 7.0f);
    const float v1 = (float)(q - 7) * (8.0f / 7.0f);
    const float t0 = copysignf(log2f(fabsf(v0) + 1.0f) * (1.0f / 3.0f), v0);
    const float t1 = copysignf(log2f(fabsf(v1) + 1.0f) * (1.0f / 3.0f), v1);
    const float ha = fmaxf(0.0f, t0 * w1[t * 2]         + t1 * w1[t * 2 + 1]         + b1[t]);
    const float hb = fmaxf(0.0f, t0 * w1[(t + 256) * 2] + t1 * w1[(t + 256) * 2 + 1] + b1[t + 256]);
    for (int h = 0; h < 8; ++h) {
        __syncthreads();
        red[t] = ha * w2[h * 512 + t] + hb * w2[h * 512 + t + 256];
        __syncthreads();
        for (int s = 128; s > 0; s >>= 1) {
            if (t < s) red[t] += red[t + s];
            __syncthreads();
        }
        if (t == 0) biastab[e * 8 + h] = 16.0f / (1.0f + expf(-red[0]));
    }
}

// ---------------- expand bias to [8][64][64] ----------------
__global__ void biasx_kernel(const float* __restrict__ biastab, float* __restrict__ biasx) {
    int h = blockIdx.x >> 6, n = blockIdx.x & 63, m = threadIdx.x;
    int idx = ((n >> 3) - (m >> 3) + 7) * 15 + ((n & 7) - (m & 7) + 7);
    biasx[((size_t)(h * 64 + n)) * 64 + m] = biastab[idx * 8 + h];
}

// ---------------- qkv GEMM: one block per (round, window); A from bf16 sidecar xb ----------------
__global__ __launch_bounds__(256, 3) void qkv_kernel(
    const ushort* __restrict__ xb, const ushort* __restrict__ qwb,
    const float* __restrict__ qb, ushort* __restrict__ q_ws,
    ushort* __restrict__ k_ws, ushort* __restrict__ vT_ws,
    int shift, int win0)
{
    __shared__ ushort xs[64 * 256];
    const int t = threadIdx.x;
    const int lwin = blockIdx.y, win = win0 + lwin;
    const int round = blockIdx.x;
    const int b = win >> 6, wh = (win >> 3) & 7, ww = win & 7;
    const int w = t >> 6, l = t & 63, lr = l & 15, lg = l >> 4;
    const int aswz = (lr & 7) << 3;
    const f32x4 zf = { 0.f, 0.f, 0.f, 0.f };

    {   // stage rolled window tokens: pure bf16 copy, swizzled
        int row = t >> 2, seg = t & 3;
        int i = row >> 3, j = row & 7;
        int rr = (wh * 8 + i + shift) & 63;
        int cc = (ww * 8 + j + shift) & 63;
        const ushort* src = xb + ((size_t)(b * 4096 + rr * 64 + cc)) * 256 + seg * 64;
        #pragma unroll
        for (int k8 = 0; k8 < 8; ++k8) {
            bf16x8 v = *reinterpret_cast<const bf16x8*>(src + k8 * 8);
            int col = seg * 64 + k8 * 8;
            *reinterpret_cast<bf16x8*>(xs + row * 256 + (col ^ ((row & 7) << 3))) = v;
        }
    }
    __syncthreads();

#define QK_LA(D, KT) { int k0_ = (KT) * 32 + lg * 8;                                        \
    _Pragma("unroll") for (int mf_ = 0; mf_ < 4; ++mf_)                                     \
        D[mf_] = *reinterpret_cast<const bf16x8*>(xs + (mf_ * 16 + lr) * 256 + (k0_ ^ aswz)); }
#define QK_LB(D, KT) { int k0_ = (KT) * 32 + lg * 8;                                        \
    _Pragma("unroll") for (int nf_ = 0; nf_ < 4; ++nf_)                                     \
        D[nf_] = *reinterpret_cast<const bf16x8*>(qwb + (size_t)(colb + nf_ * 16 + lr) * 256 + k0_); }

    const int colb = round * 256 + w * 64;
    f32x4 acc[4][4];
    #pragma unroll
    for (int mf = 0; mf < 4; ++mf)
        #pragma unroll
        for (int nf = 0; nf < 4; ++nf) acc[mf][nf] = zf;

    bf16x8 pb[3][4];
    QK_LB(pb[0], 0); QK_LB(pb[1], 1);
    #pragma unroll
    for (int kt = 0; kt < 8; ++kt) {
        if (kt + 2 < 8) QK_LB(pb[(kt + 2) % 3], kt + 2);
        bf16x8 pa[4];
        QK_LA(pa, kt);
        TILE_MFMA(acc, pa, pb[kt % 3]);
    }

    // bias add
    #pragma unroll
    for (int nf = 0; nf < 4; ++nf) {
        float bb = qb[colb + nf * 16 + lr];
        #pragma unroll
        for (int mf = 0; mf < 4; ++mf)
            #pragma unroll
            for (int r = 0; r < 4; ++r) acc[mf][nf][r] += bb;
    }

    if (round < 2) {
        float ss0[4][4], ss1[4][4];
        #pragma unroll
        for (int mf = 0; mf < 4; ++mf)
            #pragma unroll
            for (int r = 0; r < 4; ++r) {
                ss0[mf][r] = acc[mf][0][r] * acc[mf][0][r] + acc[mf][1][r] * acc[mf][1][r];
                ss1[mf][r] = acc[mf][2][r] * acc[mf][2][r] + acc[mf][3][r] * acc[mf][3][r];
            }
        #pragma unroll
        for (int m = 1; m < 16; m <<= 1)
            #pragma unroll
            for (int mf = 0; mf < 4; ++mf)
                #pragma unroll
                for (int r = 0; r < 4; ++r) {
                    ss0[mf][r] += __shfl_xor(ss0[mf][r], m);
                    ss1[mf][r] += __shfl_xor(ss1[mf][r], m);
                }
        ushort* dst = (round == 0) ? q_ws : k_ws;
        #pragma unroll
        for (int mf = 0; mf < 4; ++mf)
            #pragma unroll
            for (int r = 0; r < 4; ++r) {
                float rs0 = 1.0f / (sqrtf(ss0[mf][r]) + 1e-12f);
                float rs1 = 1.0f / (sqrtf(ss1[mf][r]) + 1e-12f);
                size_t rowoff = ((size_t)lwin * 64 + mf * 16 + lg * 4 + r) * 256;
                #pragma unroll
                for (int nf = 0; nf < 4; ++nf)
                    dst[rowoff + w * 64 + nf * 16 + lr] =
                        f2b(acc[mf][nf][r] * (nf < 2 ? rs0 : rs1));
            }
    } else {
        #pragma unroll
        for (int nf = 0; nf < 4; ++nf) {
            int h = 2 * w + (nf >> 1);
            int chan = (nf & 1) * 16 + lr;
            ushort* vrow = vT_ws + (((size_t)lwin * 8 + h) * 32 + chan) * 64;
            #pragma unroll
            for (int mf = 0; mf < 4; ++mf)
                #pragma unroll
                for (int r = 0; r < 4; ++r)
                    vrow[mf * 16 + lg * 4 + r] = f2b(acc[mf][nf][r]);
        }
    }
#undef QK_LA
#undef QK_LB
}

// ---------------- fused attention (S+softmax+PV) + proj + post-LN + residual ----------------
// epilogue maintains bf16 sidecar xbo alongside f32 xout
__global__ __launch_bounds__(256, 2) void attnproj_kernel(
    const ushort* __restrict__ q_ws, const ushort* __restrict__ k_ws,
    const ushort* __restrict__ vT_ws, const ushort* __restrict__ pwb,
    const float* __restrict__ pb, const float* __restrict__ lsc,
    const float* __restrict__ biasx, const float* __restrict__ n1s,
    const float* __restrict__ n1b, const float* __restrict__ xin,
    float* __restrict__ xout, ushort* __restrict__ xbo, int shift, int win0)
{
    extern __shared__ ushort sm[];
    ushort* aol  = sm + 4 * 64 * 72;    // [64][256] bf16, swizzled
    float*  outT = (float*)sm;          // [64][264] f32 overlay

    const int t = threadIdx.x;
    const int win = win0 + blockIdx.x, lwin = blockIdx.x;
    const int b = win >> 6, wh = (win >> 3) & 7, ww = win & 7;
    const int w = t >> 6, l = t & 63, lr = l & 15, lg = l >> 4;
    ushort* Pw = sm + w * 64 * 72;      // wave-private P
    const size_t tokbase = (size_t)lwin * 64;
    const f32x4 zf = { 0.f, 0.f, 0.f, 0.f };

    int regc[4], regr[4][4];
    #pragma unroll
    for (int nf = 0; nf < 4; ++nf) {
        int kc = nf * 16 + lr;
        int pr = wh * 8 + (kc >> 3), pc = ww * 8 + (kc & 7);
        regc[nf] = ((pr < 56) ? 0 : ((pr < 60) ? 1 : 2)) * 3 +
                   ((pc < 56) ? 0 : ((pc < 60) ? 1 : 2));
    }
    #pragma unroll
    for (int mf = 0; mf < 4; ++mf)
        #pragma unroll
        for (int r = 0; r < 4; ++r) {
            int n = mf * 16 + lg * 4 + r;
            int pr = wh * 8 + (n >> 3), pc = ww * 8 + (n & 7);
            regr[mf][r] = ((pr < 56) ? 0 : ((pr < 60) ? 1 : 2)) * 3 +
                          ((pc < 56) ? 0 : ((pc < 60) ? 1 : 2));
        }

    for (int hr = 0; hr < 2; ++hr) {
        const int h = w * 2 + hr;

        f32x4 sacc[4][4];
        {
            bf16x8 aq[4], bk[4];
            #pragma unroll
            for (int mf = 0; mf < 4; ++mf)
                aq[mf] = *reinterpret_cast<const bf16x8*>(
                    q_ws + (tokbase + mf * 16 + lr) * 256 + h * 32 + lg * 8);
            #pragma unroll
            for (int nf = 0; nf < 4; ++nf)
                bk[nf] = *reinterpret_cast<const bf16x8*>(
                    k_ws + (tokbase + nf * 16 + lr) * 256 + h * 32 + lg * 8);
            #pragma unroll
            for (int mf = 0; mf < 4; ++mf)
                #pragma unroll
                for (int nf = 0; nf < 4; ++nf)
                    sacc[mf][nf] = MFMA16(aq[mf], bk[nf], zf);
        }

        const float scale = __expf(fminf(lsc[h], 4.6051702f));
        float mx[4][4], sum[4][4];
        #pragma unroll
        for (int mf = 0; mf < 4; ++mf)
            #pragma unroll
            for (int r = 0; r < 4; ++r) mx[mf][r] = -1e30f;

        #pragma unroll
        for (int nf = 0; nf < 4; ++nf)
            #pragma unroll
            for (int mf = 0; mf < 4; ++mf)
                #pragma unroll
                for (int r = 0; r < 4; ++r) {
                    float v = sacc[mf][nf][r] * scale +
                              biasx[((size_t)(h * 64 + mf * 16 + lg * 4 + r)) * 64 + nf * 16 + lr];
                    if (shift && regc[nf] != regr[mf][r]) v -= 100.0f;
                    sacc[mf][nf][r] = v;
                    mx[mf][r] = fmaxf(mx[mf][r], v);
                }
        #pragma unroll
        for (int m = 1; m < 16; m <<= 1)
            #pragma unroll
            for (int mf = 0; mf < 4; ++mf)
                #pragma unroll
                for (int r = 0; r < 4; ++r) mx[mf][r] = fmaxf(mx[mf][r], __shfl_xor(mx[mf][r], m));

        #pragma unroll
        for (int mf = 0; mf < 4; ++mf)
            #pragma unroll
            for (int r = 0; r < 4; ++r) sum[mf][r] = 0.f;
        #pragma unroll
        for (int nf = 0; nf < 4; ++nf)
            #pragma unroll
            for (int mf = 0; mf < 4; ++mf)
                #pragma unroll
                for (int r = 0; r < 4; ++r) {
                    float e = __expf(sacc[mf][nf][r] - mx[mf][r]);
                    sacc[mf][nf][r] = e;
                    sum[mf][r] += e;
                }
        #pragma unroll
        for (int m = 1; m < 16; m <<= 1)
            #pragma unroll
            for (int mf = 0; mf < 4; ++mf)
                #pragma unroll
                for (int r = 0; r < 4; ++r) sum[mf][r] += __shfl_xor(sum[mf][r], m);

        #pragma unroll
        for (int nf = 0; nf < 4; ++nf)
            #pragma unroll
            for (int mf = 0; mf < 4; ++mf)
                #pragma unroll
                for (int r = 0; r < 4; ++r)
                    Pw[(mf * 16 + lg * 4 + r) * 72 + nf * 16 + lr] = f2b(sacc[mf][nf][r]);

        f32x4 oacc[4][2];
        #pragma unroll
        for (int mf = 0; mf < 4; ++mf)
            #pragma unroll
            for (int nf = 0; nf < 2; ++nf) oacc[mf][nf] = zf;
        #pragma unroll
        for (int ks = 0; ks < 2; ++ks) {
            bf16x8 pa[4], bv[2];
            #pragma unroll
            for (int mf = 0; mf < 4; ++mf)
                pa[mf] = *reinterpret_cast<const bf16x8*>(Pw + (mf * 16 + lr) * 72 + ks * 32 + lg * 8);
            #pragma unroll
            for (int nf = 0; nf < 2; ++nf)
                bv[nf] = *reinterpret_cast<const bf16x8*>(
                    vT_ws + (((size_t)lwin * 8 + h) * 32 + nf * 16 + lr) * 64 + ks * 32 + lg * 8);
            #pragma unroll
            for (int mf = 0; mf < 4; ++mf)
                #pragma unroll
                for (int nf = 0; nf < 2; ++nf)
                    oacc[mf][nf] = MFMA16(pa[mf], bv[nf], oacc[mf][nf]);
        }

        #pragma unroll
        for (int mf = 0; mf < 4; ++mf)
            #pragma unroll
            for (int r = 0; r < 4; ++r) {
                float inv = 1.0f / sum[mf][r];
                int row = mf * 16 + lg * 4 + r;
                #pragma unroll
                for (int nf = 0; nf < 2; ++nf) {
                    int col = h * 32 + nf * 16 + lr;
                    aol[row * 256 + (col ^ ((row & 7) << 3))] = f2b(oacc[mf][nf][r] * inv);
                }
            }
    }
    __syncthreads();

    // ---- proj GEMM: M=64, N=64 (wave slice), K=256, prefetched ----
    const int aswz = (lr & 7) << 3;
#define PJ_LA(D, KT) { int k0_ = (KT) * 32 + lg * 8;                                          \
    _Pragma("unroll") for (int mf_ = 0; mf_ < 4; ++mf_)                                       \
        D[mf_] = *reinterpret_cast<const bf16x8*>(aol + (mf_ * 16 + lr) * 256 + (k0_ ^ aswz)); }
#define PJ_LB(D, KT) { int k0_ = (KT) * 32 + lg * 8;                                          \
    _Pragma("unroll") for (int nf_ = 0; nf_ < 4; ++nf_)                                       \
        D[nf_] = *reinterpret_cast<const bf16x8*>(pwb + (size_t)(w * 64 + nf_ * 16 + lr) * 256 + k0_); }

    f32x4 acc[4][4];
    #pragma unroll
    for (int mf = 0; mf < 4; ++mf)
        #pragma unroll
        for (int nf = 0; nf < 4; ++nf) acc[mf][nf] = zf;
    {
        bf16x8 pa0[4], pb0[4], pa1[4], pb1[4];
        PJ_LA(pa0, 0); PJ_LB(pb0, 0);
        #pragma unroll
        for (int kt = 0; kt < 8; kt += 2) {
            PJ_LA(pa1, kt + 1); PJ_LB(pb1, kt + 1);
            TILE_MFMA(acc, pa0, pb0);
            if (kt + 2 < 8) { PJ_LA(pa0, kt + 2); PJ_LB(pb0, kt + 2); }
            TILE_MFMA(acc, pa1, pb1);
        }
    }
#undef PJ_LA
#undef PJ_LB
    __syncthreads();

    #pragma unroll
    for (int nf = 0; nf < 4; ++nf) {
        int c = w * 64 + nf * 16 + lr;
        float bb = pb[c];
        #pragma unroll
        for (int mf = 0; mf < 4; ++mf)
            #pragma unroll
            for (int r = 0; r < 4; ++r)
                outT[(mf * 16 + lg * 4 + r) * 264 + c] = acc[mf][nf][r] + bb;
    }
    __syncthreads();

    for (int u = 0; u < 16; ++u) {
        int tk = w * 16 + u;
        float v0 = outT[tk * 264 + l];
        float v1 = outT[tk * 264 + l + 64];
        float v2 = outT[tk * 264 + l + 128];
        float v3 = outT[tk * 264 + l + 192];
        float s = v0 + v1 + v2 + v3, ss = v0 * v0 + v1 * v1 + v2 * v2 + v3 * v3;
        for (int m = 1; m < 64; m <<= 1) { s += __shfl_xor(s, m); ss += __shfl_xor(ss, m); }
        float mean = s * (1.0f / 256.0f);
        float var  = ss * (1.0f / 256.0f) - mean * mean;
        float rs   = rsqrtf(var + 1e-5f);

        int i = tk >> 3, j = tk & 7;
        int pr = (wh * 8 + i + shift) & 63;
        int pc = (ww * 8 + j + shift) & 63;
        size_t gaddr = ((size_t)(b * 4096 + pr * 64 + pc)) * 256;
        float o0 = xin[gaddr + l]       + (v0 - mean) * rs * n1s[l]       + n1b[l];
        float o1 = xin[gaddr + l + 64]  + (v1 - mean) * rs * n1s[l + 64]  + n1b[l + 64];
        float o2 = xin[gaddr + l + 128] + (v2 - mean) * rs * n1s[l + 128] + n1b[l + 128];
        float o3 = xin[gaddr + l + 192] + (v3 - mean) * rs * n1s[l + 192] + n1b[l + 192];
        xout[gaddr + l]       = o0;  xbo[gaddr + l]       = f2b(o0);
        xout[gaddr + l + 64]  = o1;  xbo[gaddr + l + 64]  = f2b(o1);
        xout[gaddr + l + 128] = o2;  xbo[gaddr + l + 128] = f2b(o2);
        xout[gaddr + l + 192] = o3;  xbo[gaddr + l + 192] = f2b(o3);
    }
}

// ---------------- MLP GEMM1: hid = fast_gelu(xb @ w1^T + b1) -> hidb (bf16, chunk-local) ----------------
__global__ __launch_bounds__(256, 2) void mlp1_kernel(
    const ushort* __restrict__ xb, const ushort* __restrict__ w1b,
    const float* __restrict__ b1, ushort* __restrict__ hidb, int tok_base)
{
    __shared__ ushort xs[64 * 256];      // 32 KB
    __shared__ ushort hstage[64 * 256];  // 32 KB
    const int t = threadIdx.x;
    const size_t ltok0 = (size_t)blockIdx.x * 64;
    const size_t tok0  = (size_t)tok_base + ltok0;
    const int w = t >> 6, l = t & 63, lr = l & 15, lg = l >> 4;
    const int aswz = (lr & 7) << 3;
    const f32x4 zf = { 0.f, 0.f, 0.f, 0.f };

    {   // stage x tile: pure bf16 copy, swizzled
        int row = t >> 2, seg = t & 3;
        const ushort* src = xb + (tok0 + row) * 256 + seg * 64;
        #pragma unroll
        for (int k8 = 0; k8 < 8; ++k8) {
            bf16x8 v = *reinterpret_cast<const bf16x8*>(src + k8 * 8);
            int col = seg * 64 + k8 * 8;
            *reinterpret_cast<bf16x8*>(xs + row * 256 + (col ^ ((row & 7) << 3))) = v;
        }
    }
    __syncthreads();

#define M1_LA(D, KT) { int k0_ = (KT) * 32 + lg * 8;                                        \
    _Pragma("unroll") for (int mf_ = 0; mf_ < 4; ++mf_)                                     \
        D[mf_] = *reinterpret_cast<const bf16x8*>(xs + (mf_ * 16 + lr) * 256 + (k0_ ^ aswz)); }
#define M1_LB(D, KT) { int k0_ = (KT) * 32 + lg * 8;                                        \
    _Pragma("unroll") for (int nf_ = 0; nf_ < 4; ++nf_)                                     \
        D[nf_] = *reinterpret_cast<const bf16x8*>(w1b + (size_t)(n0 + nf_ * 16 + lr) * 256 + k0_); }

    for (int q = 0; q < 4; ++q) {
        const int n0 = q * 256 + w * 64;
        f32x4 acc[4][4];
        #pragma unroll
        for (int mf = 0; mf < 4; ++mf)
            #pragma unroll
            for (int nf = 0; nf < 4; ++nf) acc[mf][nf] = zf;

        bf16x8 pb[3][4];
        M1_LB(pb[0], 0); M1_LB(pb[1], 1);
        #pragma unroll
        for (int kt = 0; kt < 8; ++kt) {
            if (kt + 2 < 8) M1_LB(pb[(kt + 2) % 3], kt + 2);
            bf16x8 pa[4];
            M1_LA(pa, kt);
            TILE_MFMA(acc, pa, pb[kt % 3]);
        }

        if (q > 0) __syncthreads();

        #pragma unroll
        for (int nf = 0; nf < 4; ++nf) {
            int lcol = w * 64 + nf * 16 + lr;
            float bb = b1[q * 256 + lcol];
            #pragma unroll
            for (int mf = 0; mf < 4; ++mf)
                #pragma unroll
                for (int r = 0; r < 4; ++r)
                    hstage[(mf * 16 + lg * 4 + r) * 256 + lcol] =
                        f2b(fast_gelu(acc[mf][nf][r] + bb));
        }
        __syncthreads();

        #pragma unroll
        for (int j = 0; j < 8; ++j) {
            int c = j * 256 + t;
            int row = c >> 5, cc = (c & 31) * 8;
            *reinterpret_cast<bf16x8*>(hidb + (ltok0 + row) * 1024 + q * 256 + cc) =
                *reinterpret_cast<const bf16x8*>(hstage + row * 256 + cc);
        }
    }
#undef M1_LA
#undef M1_LB
}

// ---------------- MLP GEMM2 (LDS-staged dbuf): out = hid @ w2^T + b2, post-LN, residual ----------------
// epilogue maintains bf16 sidecar xb alongside f32 x
__global__ __launch_bounds__(256, 2) void mlp2_kernel(
    const ushort* __restrict__ hidb, const ushort* __restrict__ w2b,
    const float* __restrict__ b2, const float* __restrict__ n2s,
    const float* __restrict__ n2b, float* __restrict__ x,
    ushort* __restrict__ xb, int tok_base)
{
    extern __shared__ ushort sm3[];
    ushort* As = sm3;                   // [2][64][64]
    ushort* Bs = sm3 + 2 * 64 * 64;     // [2][4][64][64]
    float*  outT = (float*)sm3;         // [64][264] overlay (epilogue)

    const int t = threadIdx.x;
    const size_t ltok0 = (size_t)blockIdx.x * 64;
    const size_t tok0  = (size_t)tok_base + ltok0;
    const int w = t >> 6, l = t & 63, lr = l & 15, lg = l >> 4;
    const f32x4 zf = { 0.f, 0.f, 0.f, 0.f };

    const int arow = t >> 2, aslot0 = (t & 3) * 2;
    const ushort* agp = hidb + (ltok0 + arow) * 1024;
    const ushort* bgp = w2b + (size_t)(w * 64 + l) * 1024;

    bf16x8 areg[2], breg[8];
    #pragma unroll
    for (int i = 0; i < 2; ++i)
        areg[i] = *reinterpret_cast<const bf16x8*>(agp + (aslot0 + i) * 8);
    #pragma unroll
    for (int s = 0; s < 8; ++s)
        breg[s] = *reinterpret_cast<const bf16x8*>(bgp + s * 8);
    {
        ushort* aw = As + arow * 64;
        ushort* bw = Bs + (size_t)(w * 64 + l) * 64;
        #pragma unroll
        for (int i = 0; i < 2; ++i)
            *reinterpret_cast<bf16x8*>(aw + (((aslot0 + i) ^ (arow & 7)) * 8)) = areg[i];
        #pragma unroll
        for (int s = 0; s < 8; ++s)
            *reinterpret_cast<bf16x8*>(bw + ((s ^ (l & 7)) * 8)) = breg[s];
    }

    f32x4 acc[4][4];
    #pragma unroll
    for (int mf = 0; mf < 4; ++mf)
        #pragma unroll
        for (int nf = 0; nf < 4; ++nf) acc[mf][nf] = zf;

    for (int kt = 0; kt < 16; ++kt) {
        const int cur = kt & 1, nxt = cur ^ 1;
        if (kt + 1 < 16) {
            #pragma unroll
            for (int i = 0; i < 2; ++i)
                areg[i] = *reinterpret_cast<const bf16x8*>(agp + (kt + 1) * 64 + (aslot0 + i) * 8);
            #pragma unroll
            for (int s = 0; s < 8; ++s)
                breg[s] = *reinterpret_cast<const bf16x8*>(bgp + (kt + 1) * 64 + s * 8);
        }
        __syncthreads();

        const ushort* ar = As + cur * 64 * 64;
        const ushort* br = Bs + (size_t)(cur * 4 + w) * 64 * 64;
        #pragma unroll
        for (int k2 = 0; k2 < 2; ++k2) {
            bf16x8 a[4], b[4];
            #pragma unroll
            for (int mf = 0; mf < 4; ++mf)
                a[mf] = *reinterpret_cast<const bf16x8*>(
                    ar + (mf * 16 + lr) * 64 + (((k2 * 4 + lg) ^ (lr & 7)) * 8));
            #pragma unroll
            for (int nf = 0; nf < 4; ++nf)
                b[nf] = *reinterpret_cast<const bf16x8*>(
                    br + (nf * 16 + lr) * 64 + (((k2 * 4 + lg) ^ (lr & 7)) * 8));
            TILE_MFMA(acc, a, b);
        }
        __syncthreads();

        if (kt + 1 < 16) {
            ushort* aw = As + nxt * 64 * 64 + arow * 64;
            ushort* bw = Bs + (size_t)(nxt * 4 + w) * 64 * 64 + (size_t)l * 64;
            #pragma unroll
            for (int i = 0; i < 2; ++i)
                *reinterpret_cast<bf16x8*>(aw + (((aslot0 + i) ^ (arow & 7)) * 8)) = areg[i];
            #pragma unroll
            for (int s = 0; s < 8; ++s)
                *reinterpret_cast<bf16x8*>(bw + ((s ^ (l & 7)) * 8)) = breg[s];
        }
    }
    __syncthreads();

    #pragma unroll
    for (int nf = 0; nf < 4; ++nf) {
        int c = w * 64 + nf * 16 + lr;
        float bb = b2[c];
        #pragma unroll
        for (int mf = 0; mf < 4; ++mf)
            #pragma unroll
            for (int r = 0; r < 4; ++r)
                outT[(mf * 16 + lg * 4 + r) * 264 + c] = acc[mf][nf][r] + bb;
    }
    __syncthreads();

    for (int u = 0; u < 16; ++u) {
        int tk = w * 16 + u;
        float v0 = outT[tk * 264 + l];
        float v1 = outT[tk * 264 + l + 64];
        float v2 = outT[tk * 264 + l + 128];
        float v3 = outT[tk * 264 + l + 192];
        float s = v0 + v1 + v2 + v3, ss = v0 * v0 + v1 * v1 + v2 * v2 + v3 * v3;
        for (int m = 1; m < 64; m <<= 1) { s += __shfl_xor(s, m); ss += __shfl_xor(ss, m); }
        float mean = s * (1.0f / 256.0f);
        float var  = ss * (1.0f / 256.0f) - mean * mean;
        float rs   = rsqrtf(var + 1e-5f);
        float* xp = x + (tok0 + tk) * 256;
        ushort* xbp = xb + (tok0 + tk) * 256;
        float o0 = xp[l]       + (v0 - mean) * rs * n2s[l]       + n2b[l];
        float o1 = xp[l + 64]  + (v1 - mean) * rs * n2s[l + 64]  + n2b[l + 64];
        float o2 = xp[l + 128] + (v2 - mean) * rs * n2s[l + 128] + n2b[l + 128];
        float o3 = xp[l + 192] + (v3 - mean) * rs * n2s[l + 192] + n2b[l + 192];
        xp[l]       = o0;  xbp[l]       = f2b(o0);
        xp[l + 64]  = o1;  xbp[l + 64]  = f2b(o1);
        xp[l + 128] = o2;  xbp[l + 128] = f2b(o2);
        xp[l + 192] = o3;  xbp[l + 192] = f2b(o3);
    }
}

// ---------------- launcher ----------------
extern "C" void kernel_launch(void* const* d_in, const int* in_sizes, int n_in,
                              void* d_out, int out_size, void* d_ws, size_t ws_size,
                              hipStream_t stream) {
    (void)in_sizes; (void)n_in; (void)out_size;
    const float* tokens = (const float*)d_in[0];
    const float* qkv_w  = (const float*)d_in[3];
    const float* qkv_b  = (const float*)d_in[4];
    const float* lsc    = (const float*)d_in[5];
    const float* cw1    = (const float*)d_in[6];
    const float* cb1    = (const float*)d_in[7];
    const float* cw2    = (const float*)d_in[8];
    const float* pw     = (const float*)d_in[9];
    const float* pb     = (const float*)d_in[10];
    const float* n1s    = (const float*)d_in[11];
    const float* n1b    = (const float*)d_in[12];
    const float* mw1    = (const float*)d_in[13];
    const float* mb1    = (const float*)d_in[14];
    const float* mw2    = (const float*)d_in[15];
    const float* mb2    = (const float*)d_in[16];
    const float* n2s    = (const float*)d_in[17];
    const float* n2b    = (const float*)d_in[18];

    float* x = (float*)d_out;

    // ---- workspace: weights | xb (32 MB bf16 sidecar) | q/k/vT (hidb overlays q/k/vT) ----
    ushort* pwb   = (ushort*)d_ws;                       // 256 KB
    ushort* w1b   = pwb + 2 * 256 * 256;                 // 1 MB
    ushort* w2b   = w1b + 2 * 1024 * 256;                // 1 MB
    ushort* qwb   = w2b + 2 * 256 * 1024;                // 768 KB
    float*  biasx = (float*)(qwb + 2 * 768 * 256);       // 128 KB
    float*  biastab = biasx + 8 * 64 * 64;               // 1800 f32
    char*   big   = (char*)d_ws + 3407872;               // 3.25 MB offset

    ushort* xb    = (ushort*)big;                        // NTOK*256 bf16 = 32 MB
    char*   big2  = big + (size_t)NTOK * 256 * 2;

    size_t avail2 = ws_size - 3407872 - (size_t)NTOK * 256 * 2;
    // window batching: all 1024 windows if q/k/vT (96 MB) fits after xb, else halves (48 MB)
    const int hwin = (avail2 >= (size_t)3 * 1024 * 64 * 256 * 2) ? 1024 : 512;
    const int chunk_tok = (avail2 >= (size_t)32768 * 2048) ? 32768 : 16384;

    ushort* q_ws  = (ushort*)big2;
    ushort* k_ws  = q_ws + (size_t)hwin * 64 * 256;
    ushort* vT_ws = k_ws + (size_t)hwin * 64 * 256;
    ushort* hidb  = (ushort*)big2;   // overlay (q/k/vT dead during MLP; xb stays live)

    f2b_kernel<<<dim3(2 * 256 * 256 / 1024),  dim3(256), 0, stream>>>(pwb, pw);
    f2b_kernel<<<dim3(2 * 1024 * 256 / 1024), dim3(256), 0, stream>>>(w1b, mw1);
    f2b_kernel<<<dim3(2 * 256 * 1024 / 1024), dim3(256), 0, stream>>>(w2b, mw2);
    f2b_kernel<<<dim3(2 * 768 * 256 / 1024),  dim3(256), 0, stream>>>(qwb, qkv_w);
    f2b_kernel<<<dim3(NTOK * 256 / 1024),     dim3(256), 0, stream>>>(xb, tokens);  // sidecar init

    for (int l = 0; l < 2; ++l) {
        const int shift = l ? 4 : 0;
        const float* xsrc = (l == 0) ? tokens : x;   // f32 residual source
        cpb_kernel<<<dim3(225), dim3(256), 0, stream>>>(
            cw1 + (size_t)l * 1024, cb1 + (size_t)l * 512, cw2 + (size_t)l * 4096, biastab);
        biasx_kernel<<<dim3(512), dim3(64), 0, stream>>>(biastab, biasx);
        for (int win0 = 0; win0 < 1024; win0 += hwin) {
            qkv_kernel<<<dim3(3, hwin), dim3(256), 0, stream>>>(
                xb, qwb + (size_t)l * 196608, qkv_b + (size_t)l * 768,
                q_ws, k_ws, vT_ws, shift, win0);
            attnproj_kernel<<<dim3(hwin), dim3(256), AP_LDS, stream>>>(
                q_ws, k_ws, vT_ws, pwb + (size_t)l * 65536, pb + (size_t)l * 256,
                lsc + (size_t)l * 8, biasx, n1s + (size_t)l * 256, n1b + (size_t)l * 256,
                xsrc, x, xb, shift, win0);
        }
        for (int tb = 0; tb < NTOK; tb += chunk_tok) {
            mlp1_kernel<<<dim3(chunk_tok / 64), dim3(256), 0, stream>>>(
                xb, w1b + (size_t)l * 262144, mb1 + (size_t)l * 1024, hidb, tb);
            mlp2_kernel<<<dim3(chunk_tok / 64), dim3(256), MLP2_LDS, stream>>>(
                hidb, w2b + (size_t)l * 262144, mb2 + (size_t)l * 256,
                n2s + (size_t)l * 256, n2b + (size_t)l * 256, x, xb, tb);
        }
    }
}

// Round 21
// 728.366 us; speedup vs baseline: 1.0344x; 1.0299x over previous
//
#include <hip/hip_runtime.h>
#include <math.h>

// ---------------- problem constants ----------------
#define C_    256
#define NTOK  65536   // B * 64 * 64

// LDS sizes (bytes)
#define AP_LDS   (4*64*72*2 + 64*256*2)     // 69,632
#define MLP2_LDS ((2*64*64 + 2*4*64*64)*2)  // 81,920 (outT overlays)

typedef __bf16 bf16x8 __attribute__((ext_vector_type(8)));
typedef float  f32x4  __attribute__((ext_vector_type(4)));
#define MFMA16(a,b,c) __builtin_amdgcn_mfma_f32_16x16x32_bf16((a),(b),(c),0,0,0)

__device__ inline ushort f2b(float f) {
    unsigned u = __builtin_bit_cast(unsigned, f);
    return (ushort)((u + 0x7fffu + ((u >> 16) & 1u)) >> 16);   // RNE
}
__device__ inline float b2f(ushort u) {
    return __builtin_bit_cast(float, (unsigned)u << 16);
}

// fast gelu: x * sigmoid(1.59577x + 0.0713548x^3)
__device__ inline float fast_gelu(float x) {
    float u = 1.5957691216f * x + 0.0713548163f * x * x * x;
    return x * __builtin_amdgcn_rcpf(1.0f + __expf(-u));
}

union BF8u { ushort u[8]; bf16x8 v; };
__device__ inline bf16x8 cvt8(float4 a, float4 b) {
    BF8u t;
    t.u[0] = f2b(a.x); t.u[1] = f2b(a.y); t.u[2] = f2b(a.z); t.u[3] = f2b(a.w);
    t.u[4] = f2b(b.x); t.u[5] = f2b(b.y); t.u[6] = f2b(b.z); t.u[7] = f2b(b.w);
    return t.v;
}

// 16-MFMA tile update
#define TILE_MFMA(ACC, A, B)                                   \
    _Pragma("unroll") for (int mf_ = 0; mf_ < 4; ++mf_)        \
        _Pragma("unroll") for (int nf_ = 0; nf_ < 4; ++nf_)    \
            ACC[mf_][nf_] = MFMA16(A[mf_], B[nf_], ACC[mf_][nf_]);

// ---------------- f32 -> bf16 conversion (weights, tokens sidecar init) ----------------
__global__ void f2b_kernel(ushort* __restrict__ dst, const float* __restrict__ src) {
    size_t i = ((size_t)blockIdx.x * 256 + threadIdx.x) * 4;
    float4 v = *reinterpret_cast<const float4*>(src + i);
    ushort4 u = { f2b(v.x), f2b(v.y), f2b(v.z), f2b(v.w) };
    *reinterpret_cast<ushort4*>(dst + i) = u;
}

// ---------------- continuous position bias table ----------------
__global__ void cpb_kernel(const float* __restrict__ w1, const float* __restrict__ b1,
                           const float* __restrict__ w2, float* __restrict__ biastab) {
    __shared__ float red[256];
    const int e = blockIdx.x;
    const int t = threadIdx.x;
    const int p = e / 15, q = e % 15;
    const float v0 = (float)(p - 7) * (8.0f / 7.0f);
    const float v1 = (float)(q - 7) * (8.0f / 7.0f);
    const float t0 = copysignf(log2f(fabsf(v0) + 1.0f) * (1.0f / 3.0f), v0);
    const float t1 = copysignf(log2f(fabsf(v1) + 1.0f) * (1.0f / 3.0f), v1);
    const float ha = fmaxf(0.0f, t0 * w1[t * 2]         + t1 * w1[t * 2 + 1]         + b1[t]);
    const float hb = fmaxf(0.0f, t0 * w1[(t + 256) * 2] + t1 * w1[(t + 256) * 2 + 1] + b1[t + 256]);
    for (int h = 0; h < 8; ++h) {
        __syncthreads();
        red[t] = ha * w2[h * 512 + t] + hb * w2[h * 512 + t + 256];
        __syncthreads();
        for (int s = 128; s > 0; s >>= 1) {
            if (t < s) red[t] += red[t + s];
            __syncthreads();
        }
        if (t == 0) biastab[e * 8 + h] = 16.0f / (1.0f + expf(-red[0]));
    }
}

// ---------------- expand bias to [8][64][64] ----------------
__global__ void biasx_kernel(const float* __restrict__ biastab, float* __restrict__ biasx) {
    int h = blockIdx.x >> 6, n = blockIdx.x & 63, m = threadIdx.x;
    int idx = ((n >> 3) - (m >> 3) + 7) * 15 + ((n & 7) - (m & 7) + 7);
    biasx[((size_t)(h * 64 + n)) * 64 + m] = biastab[idx * 8 + h];
}

// ---------------- qkv GEMM: one block per (round, window); A from bf16 residual xb ----------------
__global__ __launch_bounds__(256, 3) void qkv_kernel(
    const ushort* __restrict__ xb, const ushort* __restrict__ qwb,
    const float* __restrict__ qb, ushort* __restrict__ q_ws,
    ushort* __restrict__ k_ws, ushort* __restrict__ vT_ws,
    int shift, int win0)
{
    __shared__ ushort xs[64 * 256];
    const int t = threadIdx.x;
    const int lwin = blockIdx.y, win = win0 + lwin;
    const int round = blockIdx.x;
    const int b = win >> 6, wh = (win >> 3) & 7, ww = win & 7;
    const int w = t >> 6, l = t & 63, lr = l & 15, lg = l >> 4;
    const int aswz = (lr & 7) << 3;
    const f32x4 zf = { 0.f, 0.f, 0.f, 0.f };

    {   // stage rolled window tokens: pure bf16 copy, swizzled
        int row = t >> 2, seg = t & 3;
        int i = row >> 3, j = row & 7;
        int rr = (wh * 8 + i + shift) & 63;
        int cc = (ww * 8 + j + shift) & 63;
        const ushort* src = xb + ((size_t)(b * 4096 + rr * 64 + cc)) * 256 + seg * 64;
        #pragma unroll
        for (int k8 = 0; k8 < 8; ++k8) {
            bf16x8 v = *reinterpret_cast<const bf16x8*>(src + k8 * 8);
            int col = seg * 64 + k8 * 8;
            *reinterpret_cast<bf16x8*>(xs + row * 256 + (col ^ ((row & 7) << 3))) = v;
        }
    }
    __syncthreads();

#define QK_LA(D, KT) { int k0_ = (KT) * 32 + lg * 8;                                        \
    _Pragma("unroll") for (int mf_ = 0; mf_ < 4; ++mf_)                                     \
        D[mf_] = *reinterpret_cast<const bf16x8*>(xs + (mf_ * 16 + lr) * 256 + (k0_ ^ aswz)); }
#define QK_LB(D, KT) { int k0_ = (KT) * 32 + lg * 8;                                        \
    _Pragma("unroll") for (int nf_ = 0; nf_ < 4; ++nf_)                                     \
        D[nf_] = *reinterpret_cast<const bf16x8*>(qwb + (size_t)(colb + nf_ * 16 + lr) * 256 + k0_); }

    const int colb = round * 256 + w * 64;
    f32x4 acc[4][4];
    #pragma unroll
    for (int mf = 0; mf < 4; ++mf)
        #pragma unroll
        for (int nf = 0; nf < 4; ++nf) acc[mf][nf] = zf;

    bf16x8 pb[3][4];
    QK_LB(pb[0], 0); QK_LB(pb[1], 1);
    #pragma unroll
    for (int kt = 0; kt < 8; ++kt) {
        if (kt + 2 < 8) QK_LB(pb[(kt + 2) % 3], kt + 2);
        bf16x8 pa[4];
        QK_LA(pa, kt);
        TILE_MFMA(acc, pa, pb[kt % 3]);
    }

    // bias add
    #pragma unroll
    for (int nf = 0; nf < 4; ++nf) {
        float bb = qb[colb + nf * 16 + lr];
        #pragma unroll
        for (int mf = 0; mf < 4; ++mf)
            #pragma unroll
            for (int r = 0; r < 4; ++r) acc[mf][nf][r] += bb;
    }

    if (round < 2) {
        float ss0[4][4], ss1[4][4];
        #pragma unroll
        for (int mf = 0; mf < 4; ++mf)
            #pragma unroll
            for (int r = 0; r < 4; ++r) {
                ss0[mf][r] = acc[mf][0][r] * acc[mf][0][r] + acc[mf][1][r] * acc[mf][1][r];
                ss1[mf][r] = acc[mf][2][r] * acc[mf][2][r] + acc[mf][3][r] * acc[mf][3][r];
            }
        #pragma unroll
        for (int m = 1; m < 16; m <<= 1)
            #pragma unroll
            for (int mf = 0; mf < 4; ++mf)
                #pragma unroll
                for (int r = 0; r < 4; ++r) {
                    ss0[mf][r] += __shfl_xor(ss0[mf][r], m);
                    ss1[mf][r] += __shfl_xor(ss1[mf][r], m);
                }
        ushort* dst = (round == 0) ? q_ws : k_ws;
        #pragma unroll
        for (int mf = 0; mf < 4; ++mf)
            #pragma unroll
            for (int r = 0; r < 4; ++r) {
                float rs0 = 1.0f / (sqrtf(ss0[mf][r]) + 1e-12f);
                float rs1 = 1.0f / (sqrtf(ss1[mf][r]) + 1e-12f);
                size_t rowoff = ((size_t)lwin * 64 + mf * 16 + lg * 4 + r) * 256;
                #pragma unroll
                for (int nf = 0; nf < 4; ++nf)
                    dst[rowoff + w * 64 + nf * 16 + lr] =
                        f2b(acc[mf][nf][r] * (nf < 2 ? rs0 : rs1));
            }
    } else {
        #pragma unroll
        for (int nf = 0; nf < 4; ++nf) {
            int h = 2 * w + (nf >> 1);
            int chan = (nf & 1) * 16 + lr;
            ushort* vrow = vT_ws + (((size_t)lwin * 8 + h) * 32 + chan) * 64;
            #pragma unroll
            for (int mf = 0; mf < 4; ++mf)
                #pragma unroll
                for (int r = 0; r < 4; ++r)
                    vrow[mf * 16 + lg * 4 + r] = f2b(acc[mf][nf][r]);
        }
    }
#undef QK_LA
#undef QK_LB
}

// ---------------- fused attention (S+softmax+PV) + proj + post-LN + residual (bf16 stream) ----------------
__global__ __launch_bounds__(256, 2) void attnproj_kernel(
    const ushort* __restrict__ q_ws, const ushort* __restrict__ k_ws,
    const ushort* __restrict__ vT_ws, const ushort* __restrict__ pwb,
    const float* __restrict__ pb, const float* __restrict__ lsc,
    const float* __restrict__ biasx, const float* __restrict__ n1s,
    const float* __restrict__ n1b, ushort* __restrict__ xb, int shift, int win0)
{
    extern __shared__ ushort sm[];
    ushort* aol  = sm + 4 * 64 * 72;    // [64][256] bf16, swizzled
    float*  outT = (float*)sm;          // [64][264] f32 overlay

    const int t = threadIdx.x;
    const int win = win0 + blockIdx.x, lwin = blockIdx.x;
    const int b = win >> 6, wh = (win >> 3) & 7, ww = win & 7;
    const int w = t >> 6, l = t & 63, lr = l & 15, lg = l >> 4;
    ushort* Pw = sm + w * 64 * 72;      // wave-private P
    const size_t tokbase = (size_t)lwin * 64;
    const f32x4 zf = { 0.f, 0.f, 0.f, 0.f };

    int regc[4], regr[4][4];
    #pragma unroll
    for (int nf = 0; nf < 4; ++nf) {
        int kc = nf * 16 + lr;
        int pr = wh * 8 + (kc >> 3), pc = ww * 8 + (kc & 7);
        regc[nf] = ((pr < 56) ? 0 : ((pr < 60) ? 1 : 2)) * 3 +
                   ((pc < 56) ? 0 : ((pc < 60) ? 1 : 2));
    }
    #pragma unroll
    for (int mf = 0; mf < 4; ++mf)
        #pragma unroll
        for (int r = 0; r < 4; ++r) {
            int n = mf * 16 + lg * 4 + r;
            int pr = wh * 8 + (n >> 3), pc = ww * 8 + (n & 7);
            regr[mf][r] = ((pr < 56) ? 0 : ((pr < 60) ? 1 : 2)) * 3 +
                          ((pc < 56) ? 0 : ((pc < 60) ? 1 : 2));
        }

    for (int hr = 0; hr < 2; ++hr) {
        const int h = w * 2 + hr;

        f32x4 sacc[4][4];
        {
            bf16x8 aq[4], bk[4];
            #pragma unroll
            for (int mf = 0; mf < 4; ++mf)
                aq[mf] = *reinterpret_cast<const bf16x8*>(
                    q_ws + (tokbase + mf * 16 + lr) * 256 + h * 32 + lg * 8);
            #pragma unroll
            for (int nf = 0; nf < 4; ++nf)
                bk[nf] = *reinterpret_cast<const bf16x8*>(
                    k_ws + (tokbase + nf * 16 + lr) * 256 + h * 32 + lg * 8);
            #pragma unroll
            for (int mf = 0; mf < 4; ++mf)
                #pragma unroll
                for (int nf = 0; nf < 4; ++nf)
                    sacc[mf][nf] = MFMA16(aq[mf], bk[nf], zf);
        }

        const float scale = __expf(fminf(lsc[h], 4.6051702f));
        float mx[4][4], sum[4][4];
        #pragma unroll
        for (int mf = 0; mf < 4; ++mf)
            #pragma unroll
            for (int r = 0; r < 4; ++r) mx[mf][r] = -1e30f;

        #pragma unroll
        for (int nf = 0; nf < 4; ++nf)
            #pragma unroll
            for (int mf = 0; mf < 4; ++mf)
                #pragma unroll
                for (int r = 0; r < 4; ++r) {
                    float v = sacc[mf][nf][r] * scale +
                              biasx[((size_t)(h * 64 + mf * 16 + lg * 4 + r)) * 64 + nf * 16 + lr];
                    if (shift && regc[nf] != regr[mf][r]) v -= 100.0f;
                    sacc[mf][nf][r] = v;
                    mx[mf][r] = fmaxf(mx[mf][r], v);
                }
        #pragma unroll
        for (int m = 1; m < 16; m <<= 1)
            #pragma unroll
            for (int mf = 0; mf < 4; ++mf)
                #pragma unroll
                for (int r = 0; r < 4; ++r) mx[mf][r] = fmaxf(mx[mf][r], __shfl_xor(mx[mf][r], m));

        #pragma unroll
        for (int mf = 0; mf < 4; ++mf)
            #pragma unroll
            for (int r = 0; r < 4; ++r) sum[mf][r] = 0.f;
        #pragma unroll
        for (int nf = 0; nf < 4; ++nf)
            #pragma unroll
            for (int mf = 0; mf < 4; ++mf)
                #pragma unroll
                for (int r = 0; r < 4; ++r) {
                    float e = __expf(sacc[mf][nf][r] - mx[mf][r]);
                    sacc[mf][nf][r] = e;
                    sum[mf][r] += e;
                }
        #pragma unroll
        for (int m = 1; m < 16; m <<= 1)
            #pragma unroll
            for (int mf = 0; mf < 4; ++mf)
                #pragma unroll
                for (int r = 0; r < 4; ++r) sum[mf][r] += __shfl_xor(sum[mf][r], m);

        #pragma unroll
        for (int nf = 0; nf < 4; ++nf)
            #pragma unroll
            for (int mf = 0; mf < 4; ++mf)
                #pragma unroll
                for (int r = 0; r < 4; ++r)
                    Pw[(mf * 16 + lg * 4 + r) * 72 + nf * 16 + lr] = f2b(sacc[mf][nf][r]);

        f32x4 oacc[4][2];
        #pragma unroll
        for (int mf = 0; mf < 4; ++mf)
            #pragma unroll
            for (int nf = 0; nf < 2; ++nf) oacc[mf][nf] = zf;
        #pragma unroll
        for (int ks = 0; ks < 2; ++ks) {
            bf16x8 pa[4], bv[2];
            #pragma unroll
            for (int mf = 0; mf < 4; ++mf)
                pa[mf] = *reinterpret_cast<const bf16x8*>(Pw + (mf * 16 + lr) * 72 + ks * 32 + lg * 8);
            #pragma unroll
            for (int nf = 0; nf < 2; ++nf)
                bv[nf] = *reinterpret_cast<const bf16x8*>(
                    vT_ws + (((size_t)lwin * 8 + h) * 32 + nf * 16 + lr) * 64 + ks * 32 + lg * 8);
            #pragma unroll
            for (int mf = 0; mf < 4; ++mf)
                #pragma unroll
                for (int nf = 0; nf < 2; ++nf)
                    oacc[mf][nf] = MFMA16(pa[mf], bv[nf], oacc[mf][nf]);
        }

        #pragma unroll
        for (int mf = 0; mf < 4; ++mf)
            #pragma unroll
            for (int r = 0; r < 4; ++r) {
                float inv = 1.0f / sum[mf][r];
                int row = mf * 16 + lg * 4 + r;
                #pragma unroll
                for (int nf = 0; nf < 2; ++nf) {
                    int col = h * 32 + nf * 16 + lr;
                    aol[row * 256 + (col ^ ((row & 7) << 3))] = f2b(oacc[mf][nf][r] * inv);
                }
            }
    }
    __syncthreads();

    // ---- proj GEMM: M=64, N=64 (wave slice), K=256, prefetched ----
    const int aswz = (lr & 7) << 3;
#define PJ_LA(D, KT) { int k0_ = (KT) * 32 + lg * 8;                                          \
    _Pragma("unroll") for (int mf_ = 0; mf_ < 4; ++mf_)                                       \
        D[mf_] = *reinterpret_cast<const bf16x8*>(aol + (mf_ * 16 + lr) * 256 + (k0_ ^ aswz)); }
#define PJ_LB(D, KT) { int k0_ = (KT) * 32 + lg * 8;                                          \
    _Pragma("unroll") for (int nf_ = 0; nf_ < 4; ++nf_)                                       \
        D[nf_] = *reinterpret_cast<const bf16x8*>(pwb + (size_t)(w * 64 + nf_ * 16 + lr) * 256 + k0_); }

    f32x4 acc[4][4];
    #pragma unroll
    for (int mf = 0; mf < 4; ++mf)
        #pragma unroll
        for (int nf = 0; nf < 4; ++nf) acc[mf][nf] = zf;
    {
        bf16x8 pa0[4], pb0[4], pa1[4], pb1[4];
        PJ_LA(pa0, 0); PJ_LB(pb0, 0);
        #pragma unroll
        for (int kt = 0; kt < 8; kt += 2) {
            PJ_LA(pa1, kt + 1); PJ_LB(pb1, kt + 1);
            TILE_MFMA(acc, pa0, pb0);
            if (kt + 2 < 8) { PJ_LA(pa0, kt + 2); PJ_LB(pb0, kt + 2); }
            TILE_MFMA(acc, pa1, pb1);
        }
    }
#undef PJ_LA
#undef PJ_LB
    __syncthreads();

    #pragma unroll
    for (int nf = 0; nf < 4; ++nf) {
        int c = w * 64 + nf * 16 + lr;
        float bb = pb[c];
        #pragma unroll
        for (int mf = 0; mf < 4; ++mf)
            #pragma unroll
            for (int r = 0; r < 4; ++r)
                outT[(mf * 16 + lg * 4 + r) * 264 + c] = acc[mf][nf][r] + bb;
    }
    __syncthreads();

    for (int u = 0; u < 16; ++u) {
        int tk = w * 16 + u;
        float v0 = outT[tk * 264 + l];
        float v1 = outT[tk * 264 + l + 64];
        float v2 = outT[tk * 264 + l + 128];
        float v3 = outT[tk * 264 + l + 192];
        float s = v0 + v1 + v2 + v3, ss = v0 * v0 + v1 * v1 + v2 * v2 + v3 * v3;
        for (int m = 1; m < 64; m <<= 1) { s += __shfl_xor(s, m); ss += __shfl_xor(ss, m); }
        float mean = s * (1.0f / 256.0f);
        float var  = ss * (1.0f / 256.0f) - mean * mean;
        float rs   = rsqrtf(var + 1e-5f);

        int i = tk >> 3, j = tk & 7;
        int pr = (wh * 8 + i + shift) & 63;
        int pc = (ww * 8 + j + shift) & 63;
        size_t gaddr = ((size_t)(b * 4096 + pr * 64 + pc)) * 256;
        float o0 = b2f(xb[gaddr + l])       + (v0 - mean) * rs * n1s[l]       + n1b[l];
        float o1 = b2f(xb[gaddr + l + 64])  + (v1 - mean) * rs * n1s[l + 64]  + n1b[l + 64];
        float o2 = b2f(xb[gaddr + l + 128]) + (v2 - mean) * rs * n1s[l + 128] + n1b[l + 128];
        float o3 = b2f(xb[gaddr + l + 192]) + (v3 - mean) * rs * n1s[l + 192] + n1b[l + 192];
        xb[gaddr + l]       = f2b(o0);
        xb[gaddr + l + 64]  = f2b(o1);
        xb[gaddr + l + 128] = f2b(o2);
        xb[gaddr + l + 192] = f2b(o3);
    }
}

// ---------------- MLP GEMM1: hid = fast_gelu(xb @ w1^T + b1) -> hidb (bf16, chunk-local) ----------------
__global__ __launch_bounds__(256, 2) void mlp1_kernel(
    const ushort* __restrict__ xb, const ushort* __restrict__ w1b,
    const float* __restrict__ b1, ushort* __restrict__ hidb, int tok_base)
{
    __shared__ ushort xs[64 * 256];      // 32 KB
    __shared__ ushort hstage[64 * 256];  // 32 KB
    const int t = threadIdx.x;
    const size_t ltok0 = (size_t)blockIdx.x * 64;
    const size_t tok0  = (size_t)tok_base + ltok0;
    const int w = t >> 6, l = t & 63, lr = l & 15, lg = l >> 4;
    const int aswz = (lr & 7) << 3;
    const f32x4 zf = { 0.f, 0.f, 0.f, 0.f };

    {   // stage x tile: pure bf16 copy, swizzled
        int row = t >> 2, seg = t & 3;
        const ushort* src = xb + (tok0 + row) * 256 + seg * 64;
        #pragma unroll
        for (int k8 = 0; k8 < 8; ++k8) {
            bf16x8 v = *reinterpret_cast<const bf16x8*>(src + k8 * 8);
            int col = seg * 64 + k8 * 8;
            *reinterpret_cast<bf16x8*>(xs + row * 256 + (col ^ ((row & 7) << 3))) = v;
        }
    }
    __syncthreads();

#define M1_LA(D, KT) { int k0_ = (KT) * 32 + lg * 8;                                        \
    _Pragma("unroll") for (int mf_ = 0; mf_ < 4; ++mf_)                                     \
        D[mf_] = *reinterpret_cast<const bf16x8*>(xs + (mf_ * 16 + lr) * 256 + (k0_ ^ aswz)); }
#define M1_LB(D, KT) { int k0_ = (KT) * 32 + lg * 8;                                        \
    _Pragma("unroll") for (int nf_ = 0; nf_ < 4; ++nf_)                                     \
        D[nf_] = *reinterpret_cast<const bf16x8*>(w1b + (size_t)(n0 + nf_ * 16 + lr) * 256 + k0_); }

    for (int q = 0; q < 4; ++q) {
        const int n0 = q * 256 + w * 64;
        f32x4 acc[4][4];
        #pragma unroll
        for (int mf = 0; mf < 4; ++mf)
            #pragma unroll
            for (int nf = 0; nf < 4; ++nf) acc[mf][nf] = zf;

        bf16x8 pb[3][4];
        M1_LB(pb[0], 0); M1_LB(pb[1], 1);
        #pragma unroll
        for (int kt = 0; kt < 8; ++kt) {
            if (kt + 2 < 8) M1_LB(pb[(kt + 2) % 3], kt + 2);
            bf16x8 pa[4];
            M1_LA(pa, kt);
            TILE_MFMA(acc, pa, pb[kt % 3]);
        }

        if (q > 0) __syncthreads();

        #pragma unroll
        for (int nf = 0; nf < 4; ++nf) {
            int lcol = w * 64 + nf * 16 + lr;
            float bb = b1[q * 256 + lcol];
            #pragma unroll
            for (int mf = 0; mf < 4; ++mf)
                #pragma unroll
                for (int r = 0; r < 4; ++r)
                    hstage[(mf * 16 + lg * 4 + r) * 256 + lcol] =
                        f2b(fast_gelu(acc[mf][nf][r] + bb));
        }
        __syncthreads();

        #pragma unroll
        for (int j = 0; j < 8; ++j) {
            int c = j * 256 + t;
            int row = c >> 5, cc = (c & 31) * 8;
            *reinterpret_cast<bf16x8*>(hidb + (ltok0 + row) * 1024 + q * 256 + cc) =
                *reinterpret_cast<const bf16x8*>(hstage + row * 256 + cc);
        }
    }
#undef M1_LA
#undef M1_LB
}

// ---------------- MLP GEMM2 (LDS-staged dbuf): out = hid @ w2^T + b2, post-LN, residual ----------------
// residual from bf16 xb; writes xb (non-final) or f32 x=d_out (final layer)
__global__ __launch_bounds__(256, 2) void mlp2_kernel(
    const ushort* __restrict__ hidb, const ushort* __restrict__ w2b,
    const float* __restrict__ b2, const float* __restrict__ n2s,
    const float* __restrict__ n2b, float* __restrict__ x,
    ushort* __restrict__ xb, int tok_base, int last)
{
    extern __shared__ ushort sm3[];
    ushort* As = sm3;                   // [2][64][64]
    ushort* Bs = sm3 + 2 * 64 * 64;     // [2][4][64][64]
    float*  outT = (float*)sm3;         // [64][264] overlay (epilogue)

    const int t = threadIdx.x;
    const size_t ltok0 = (size_t)blockIdx.x * 64;
    const size_t tok0  = (size_t)tok_base + ltok0;
    const int w = t >> 6, l = t & 63, lr = l & 15, lg = l >> 4;
    const f32x4 zf = { 0.f, 0.f, 0.f, 0.f };

    const int arow = t >> 2, aslot0 = (t & 3) * 2;
    const ushort* agp = hidb + (ltok0 + arow) * 1024;
    const ushort* bgp = w2b + (size_t)(w * 64 + l) * 1024;

    bf16x8 areg[2], breg[8];
    #pragma unroll
    for (int i = 0; i < 2; ++i)
        areg[i] = *reinterpret_cast<const bf16x8*>(agp + (aslot0 + i) * 8);
    #pragma unroll
    for (int s = 0; s < 8; ++s)
        breg[s] = *reinterpret_cast<const bf16x8*>(bgp + s * 8);
    {
        ushort* aw = As + arow * 64;
        ushort* bw = Bs + (size_t)(w * 64 + l) * 64;
        #pragma unroll
        for (int i = 0; i < 2; ++i)
            *reinterpret_cast<bf16x8*>(aw + (((aslot0 + i) ^ (arow & 7)) * 8)) = areg[i];
        #pragma unroll
        for (int s = 0; s < 8; ++s)
            *reinterpret_cast<bf16x8*>(bw + ((s ^ (l & 7)) * 8)) = breg[s];
    }

    f32x4 acc[4][4];
    #pragma unroll
    for (int mf = 0; mf < 4; ++mf)
        #pragma unroll
        for (int nf = 0; nf < 4; ++nf) acc[mf][nf] = zf;

    for (int kt = 0; kt < 16; ++kt) {
        const int cur = kt & 1, nxt = cur ^ 1;
        if (kt + 1 < 16) {
            #pragma unroll
            for (int i = 0; i < 2; ++i)
                areg[i] = *reinterpret_cast<const bf16x8*>(agp + (kt + 1) * 64 + (aslot0 + i) * 8);
            #pragma unroll
            for (int s = 0; s < 8; ++s)
                breg[s] = *reinterpret_cast<const bf16x8*>(bgp + (kt + 1) * 64 + s * 8);
        }
        __syncthreads();

        const ushort* ar = As + cur * 64 * 64;
        const ushort* br = Bs + (size_t)(cur * 4 + w) * 64 * 64;
        #pragma unroll
        for (int k2 = 0; k2 < 2; ++k2) {
            bf16x8 a[4], b[4];
            #pragma unroll
            for (int mf = 0; mf < 4; ++mf)
                a[mf] = *reinterpret_cast<const bf16x8*>(
                    ar + (mf * 16 + lr) * 64 + (((k2 * 4 + lg) ^ (lr & 7)) * 8));
            #pragma unroll
            for (int nf = 0; nf < 4; ++nf)
                b[nf] = *reinterpret_cast<const bf16x8*>(
                    br + (nf * 16 + lr) * 64 + (((k2 * 4 + lg) ^ (lr & 7)) * 8));
            TILE_MFMA(acc, a, b);
        }
        __syncthreads();

        if (kt + 1 < 16) {
            ushort* aw = As + nxt * 64 * 64 + arow * 64;
            ushort* bw = Bs + (size_t)(nxt * 4 + w) * 64 * 64 + (size_t)l * 64;
            #pragma unroll
            for (int i = 0; i < 2; ++i)
                *reinterpret_cast<bf16x8*>(aw + (((aslot0 + i) ^ (arow & 7)) * 8)) = areg[i];
            #pragma unroll
            for (int s = 0; s < 8; ++s)
                *reinterpret_cast<bf16x8*>(bw + ((s ^ (l & 7)) * 8)) = breg[s];
        }
    }
    __syncthreads();

    #pragma unroll
    for (int nf = 0; nf < 4; ++nf) {
        int c = w * 64 + nf * 16 + lr;
        float bb = b2[c];
        #pragma unroll
        for (int mf = 0; mf < 4; ++mf)
            #pragma unroll
            for (int r = 0; r < 4; ++r)
                outT[(mf * 16 + lg * 4 + r) * 264 + c] = acc[mf][nf][r] + bb;
    }
    __syncthreads();

    for (int u = 0; u < 16; ++u) {
        int tk = w * 16 + u;
        float v0 = outT[tk * 264 + l];
        float v1 = outT[tk * 264 + l + 64];
        float v2 = outT[tk * 264 + l + 128];
        float v3 = outT[tk * 264 + l + 192];
        float s = v0 + v1 + v2 + v3, ss = v0 * v0 + v1 * v1 + v2 * v2 + v3 * v3;
        for (int m = 1; m < 64; m <<= 1) { s += __shfl_xor(s, m); ss += __shfl_xor(ss, m); }
        float mean = s * (1.0f / 256.0f);
        float var  = ss * (1.0f / 256.0f) - mean * mean;
        float rs   = rsqrtf(var + 1e-5f);
        ushort* xbp = xb + (tok0 + tk) * 256;
        float o0 = b2f(xbp[l])       + (v0 - mean) * rs * n2s[l]       + n2b[l];
        float o1 = b2f(xbp[l + 64])  + (v1 - mean) * rs * n2s[l + 64]  + n2b[l + 64];
        float o2 = b2f(xbp[l + 128]) + (v2 - mean) * rs * n2s[l + 128] + n2b[l + 128];
        float o3 = b2f(xbp[l + 192]) + (v3 - mean) * rs * n2s[l + 192] + n2b[l + 192];
        if (last) {
            float* xp = x + (tok0 + tk) * 256;
            xp[l]       = o0;
            xp[l + 64]  = o1;
            xp[l + 128] = o2;
            xp[l + 192] = o3;
        } else {
            xbp[l]       = f2b(o0);
            xbp[l + 64]  = f2b(o1);
            xbp[l + 128] = f2b(o2);
            xbp[l + 192] = f2b(o3);
        }
    }
}

// ---------------- launcher ----------------
extern "C" void kernel_launch(void* const* d_in, const int* in_sizes, int n_in,
                              void* d_out, int out_size, void* d_ws, size_t ws_size,
                              hipStream_t stream) {
    (void)in_sizes; (void)n_in; (void)out_size;
    const float* tokens = (const float*)d_in[0];
    const float* qkv_w  = (const float*)d_in[3];
    const float* qkv_b  = (const float*)d_in[4];
    const float* lsc    = (const float*)d_in[5];
    const float* cw1    = (const float*)d_in[6];
    const float* cb1    = (const float*)d_in[7];
    const float* cw2    = (const float*)d_in[8];
    const float* pw     = (const float*)d_in[9];
    const float* pb     = (const float*)d_in[10];
    const float* n1s    = (const float*)d_in[11];
    const float* n1b    = (const float*)d_in[12];
    const float* mw1    = (const float*)d_in[13];
    const float* mb1    = (const float*)d_in[14];
    const float* mw2    = (const float*)d_in[15];
    const float* mb2    = (const float*)d_in[16];
    const float* n2s    = (const float*)d_in[17];
    const float* n2b    = (const float*)d_in[18];

    float* x = (float*)d_out;

    // ---- workspace: weights | xb (32 MB bf16 residual stream) | q/k/vT (hidb overlays) ----
    ushort* pwb   = (ushort*)d_ws;                       // 256 KB
    ushort* w1b   = pwb + 2 * 256 * 256;                 // 1 MB
    ushort* w2b   = w1b + 2 * 1024 * 256;                // 1 MB
    ushort* qwb   = w2b + 2 * 256 * 1024;                // 768 KB
    float*  biasx = (float*)(qwb + 2 * 768 * 256);       // 128 KB
    float*  biastab = biasx + 8 * 64 * 64;               // 1800 f32
    char*   big   = (char*)d_ws + 3407872;               // 3.25 MB offset

    ushort* xb    = (ushort*)big;                        // NTOK*256 bf16 = 32 MB
    char*   big2  = big + (size_t)NTOK * 256 * 2;

    size_t avail2 = ws_size - 3407872 - (size_t)NTOK * 256 * 2;
    const int hwin = (avail2 >= (size_t)3 * 1024 * 64 * 256 * 2) ? 1024 : 512;
    const int chunk_tok = (avail2 >= (size_t)32768 * 2048) ? 32768 : 16384;

    ushort* q_ws  = (ushort*)big2;
    ushort* k_ws  = q_ws + (size_t)hwin * 64 * 256;
    ushort* vT_ws = k_ws + (size_t)hwin * 64 * 256;
    ushort* hidb  = (ushort*)big2;   // overlay (q/k/vT dead during MLP; xb stays live)

    f2b_kernel<<<dim3(2 * 256 * 256 / 1024),  dim3(256), 0, stream>>>(pwb, pw);
    f2b_kernel<<<dim3(2 * 1024 * 256 / 1024), dim3(256), 0, stream>>>(w1b, mw1);
    f2b_kernel<<<dim3(2 * 256 * 1024 / 1024), dim3(256), 0, stream>>>(w2b, mw2);
    f2b_kernel<<<dim3(2 * 768 * 256 / 1024),  dim3(256), 0, stream>>>(qwb, qkv_w);
    f2b_kernel<<<dim3(NTOK * 256 / 1024),     dim3(256), 0, stream>>>(xb, tokens);  // stream init

    for (int l = 0; l < 2; ++l) {
        const int shift = l ? 4 : 0;
        cpb_kernel<<<dim3(225), dim3(256), 0, stream>>>(
            cw1 + (size_t)l * 1024, cb1 + (size_t)l * 512, cw2 + (size_t)l * 4096, biastab);
        biasx_kernel<<<dim3(512), dim3(64), 0, stream>>>(biastab, biasx);
        for (int win0 = 0; win0 < 1024; win0 += hwin) {
            qkv_kernel<<<dim3(3, hwin), dim3(256), 0, stream>>>(
                xb, qwb + (size_t)l * 196608, qkv_b + (size_t)l * 768,
                q_ws, k_ws, vT_ws, shift, win0);
            attnproj_kernel<<<dim3(hwin), dim3(256), AP_LDS, stream>>>(
                q_ws, k_ws, vT_ws, pwb + (size_t)l * 65536, pb + (size_t)l * 256,
                lsc + (size_t)l * 8, biasx, n1s + (size_t)l * 256, n1b + (size_t)l * 256,
                xb, shift, win0);
        }
        for (int tb = 0; tb < NTOK; tb += chunk_tok) {
            mlp1_kernel<<<dim3(chunk_tok / 64), dim3(256), 0, stream>>>(
                xb, w1b + (size_t)l * 262144, mb1 + (size_t)l * 1024, hidb, tb);
            mlp2_kernel<<<dim3(chunk_tok / 64), dim3(256), MLP2_LDS, stream>>>(
                hidb, w2b + (size_t)l * 262144, mb2 + (size_t)l * 256,
                n2s + (size_t)l * 256, n2b + (size_t)l * 256, x, xb, tb, l == 1 ? 1 : 0);
        }
    }
}

// Round 22
// 709.543 us; speedup vs baseline: 1.0619x; 1.0265x over previous
//
#include <hip/hip_runtime.h>
#include <math.h>

// ---------------- problem constants ----------------
#define C_    256
#define NTOK  65536   // B * 64 * 64

// LDS sizes (bytes)
#define AP_LDS   (4*64*72*2 + 64*256*2)     // 69,632
#define MLP2_LDS ((2*64*64 + 2*4*64*64)*2)  // 81,920 (outT overlays)

typedef __bf16 bf16x8 __attribute__((ext_vector_type(8)));
typedef float  f32x4  __attribute__((ext_vector_type(4)));
#define MFMA16(a,b,c) __builtin_amdgcn_mfma_f32_16x16x32_bf16((a),(b),(c),0,0,0)

__device__ inline ushort f2b(float f) {
    unsigned u = __builtin_bit_cast(unsigned, f);
    return (ushort)((u + 0x7fffu + ((u >> 16) & 1u)) >> 16);   // RNE
}
__device__ inline float b2f(ushort u) {
    return __builtin_bit_cast(float, (unsigned)u << 16);
}

// fast gelu: x * sigmoid(1.59577x + 0.0713548x^3)
__device__ inline float fast_gelu(float x) {
    float u = 1.5957691216f * x + 0.0713548163f * x * x * x;
    return x * __builtin_amdgcn_rcpf(1.0f + __expf(-u));
}

union BF8u { ushort u[8]; bf16x8 v; };
__device__ inline bf16x8 cvt8(float4 a, float4 b) {
    BF8u t;
    t.u[0] = f2b(a.x); t.u[1] = f2b(a.y); t.u[2] = f2b(a.z); t.u[3] = f2b(a.w);
    t.u[4] = f2b(b.x); t.u[5] = f2b(b.y); t.u[6] = f2b(b.z); t.u[7] = f2b(b.w);
    return t.v;
}

// 16-MFMA tile update
#define TILE_MFMA(ACC, A, B)                                   \
    _Pragma("unroll") for (int mf_ = 0; mf_ < 4; ++mf_)        \
        _Pragma("unroll") for (int nf_ = 0; nf_ < 4; ++nf_)    \
            ACC[mf_][nf_] = MFMA16(A[mf_], B[nf_], ACC[mf_][nf_]);

// ---------------- f32 -> bf16 conversion (weights, stream init) ----------------
__global__ void f2b_kernel(ushort* __restrict__ dst, const float* __restrict__ src) {
    size_t i = ((size_t)blockIdx.x * 256 + threadIdx.x) * 4;
    float4 v = *reinterpret_cast<const float4*>(src + i);
    ushort4 u = { f2b(v.x), f2b(v.y), f2b(v.z), f2b(v.w) };
    *reinterpret_cast<ushort4*>(dst + i) = u;
}

// ---------------- continuous position bias table (wave-parallel) ----------------
__global__ void cpb_kernel(const float* __restrict__ w1, const float* __restrict__ b1,
                           const float* __restrict__ w2, float* __restrict__ biastab) {
    __shared__ float hs[512];
    const int e = blockIdx.x;
    const int t = threadIdx.x;
    const int p = e / 15, q = e % 15;
    const float v0 = (float)(p - 7) * (8.0f / 7.0f);
    const float v1 = (float)(q - 7) * (8.0f / 7.0f);
    const float t0 = copysignf(log2f(fabsf(v0) + 1.0f) * (1.0f / 3.0f), v0);
    const float t1 = copysignf(log2f(fabsf(v1) + 1.0f) * (1.0f / 3.0f), v1);
    hs[t]       = fmaxf(0.0f, t0 * w1[t * 2]         + t1 * w1[t * 2 + 1]         + b1[t]);
    hs[t + 256] = fmaxf(0.0f, t0 * w1[(t + 256) * 2] + t1 * w1[(t + 256) * 2 + 1] + b1[t + 256]);
    __syncthreads();
    const int w = t >> 6, l = t & 63;
    #pragma unroll
    for (int p2 = 0; p2 < 2; ++p2) {
        const int h = w * 2 + p2;
        float s = 0.f;
        #pragma unroll
        for (int j = 0; j < 8; ++j)
            s += hs[l + 64 * j] * w2[h * 512 + l + 64 * j];
        #pragma unroll
        for (int m = 1; m < 64; m <<= 1) s += __shfl_xor(s, m);
        if (l == 0) biastab[e * 8 + h] = 16.0f / (1.0f + __expf(-s));
    }
}

// ---------------- expand bias to [8][64][64] ----------------
__global__ void biasx_kernel(const float* __restrict__ biastab, float* __restrict__ biasx) {
    int h = blockIdx.x >> 6, n = blockIdx.x & 63, m = threadIdx.x;
    int idx = ((n >> 3) - (m >> 3) + 7) * 15 + ((n & 7) - (m & 7) + 7);
    biasx[((size_t)(h * 64 + n)) * 64 + m] = biastab[idx * 8 + h];
}

// ---------------- qkv GEMM: one block per (round, window); A from bf16 residual xb ----------------
__global__ __launch_bounds__(256, 4) void qkv_kernel(
    const ushort* __restrict__ xb, const ushort* __restrict__ qwb,
    const float* __restrict__ qb, ushort* __restrict__ q_ws,
    ushort* __restrict__ k_ws, ushort* __restrict__ vT_ws,
    int shift, int win0)
{
    __shared__ ushort xs[64 * 256];
    const int t = threadIdx.x;
    const int lwin = blockIdx.y, win = win0 + lwin;
    const int round = blockIdx.x;
    const int b = win >> 6, wh = (win >> 3) & 7, ww = win & 7;
    const int w = t >> 6, l = t & 63, lr = l & 15, lg = l >> 4;
    const int aswz = (lr & 7) << 3;
    const f32x4 zf = { 0.f, 0.f, 0.f, 0.f };

    {   // stage rolled window tokens: pure bf16 copy, swizzled
        int row = t >> 2, seg = t & 3;
        int i = row >> 3, j = row & 7;
        int rr = (wh * 8 + i + shift) & 63;
        int cc = (ww * 8 + j + shift) & 63;
        const ushort* src = xb + ((size_t)(b * 4096 + rr * 64 + cc)) * 256 + seg * 64;
        #pragma unroll
        for (int k8 = 0; k8 < 8; ++k8) {
            bf16x8 v = *reinterpret_cast<const bf16x8*>(src + k8 * 8);
            int col = seg * 64 + k8 * 8;
            *reinterpret_cast<bf16x8*>(xs + row * 256 + (col ^ ((row & 7) << 3))) = v;
        }
    }
    __syncthreads();

#define QK_LA(D, KT) { int k0_ = (KT) * 32 + lg * 8;                                        \
    _Pragma("unroll") for (int mf_ = 0; mf_ < 4; ++mf_)                                     \
        D[mf_] = *reinterpret_cast<const bf16x8*>(xs + (mf_ * 16 + lr) * 256 + (k0_ ^ aswz)); }
#define QK_LB(D, KT) { int k0_ = (KT) * 32 + lg * 8;                                        \
    _Pragma("unroll") for (int nf_ = 0; nf_ < 4; ++nf_)                                     \
        D[nf_] = *reinterpret_cast<const bf16x8*>(qwb + (size_t)(colb + nf_ * 16 + lr) * 256 + k0_); }

    const int colb = round * 256 + w * 64;
    f32x4 acc[4][4];
    #pragma unroll
    for (int mf = 0; mf < 4; ++mf)
        #pragma unroll
        for (int nf = 0; nf < 4; ++nf) acc[mf][nf] = zf;

    bf16x8 pb[3][4];
    QK_LB(pb[0], 0); QK_LB(pb[1], 1);
    #pragma unroll
    for (int kt = 0; kt < 8; ++kt) {
        if (kt + 2 < 8) QK_LB(pb[(kt + 2) % 3], kt + 2);
        bf16x8 pa[4];
        QK_LA(pa, kt);
        TILE_MFMA(acc, pa, pb[kt % 3]);
    }

    // bias add
    #pragma unroll
    for (int nf = 0; nf < 4; ++nf) {
        float bb = qb[colb + nf * 16 + lr];
        #pragma unroll
        for (int mf = 0; mf < 4; ++mf)
            #pragma unroll
            for (int r = 0; r < 4; ++r) acc[mf][nf][r] += bb;
    }

    if (round < 2) {
        float ss0[4][4], ss1[4][4];
        #pragma unroll
        for (int mf = 0; mf < 4; ++mf)
            #pragma unroll
            for (int r = 0; r < 4; ++r) {
                ss0[mf][r] = acc[mf][0][r] * acc[mf][0][r] + acc[mf][1][r] * acc[mf][1][r];
                ss1[mf][r] = acc[mf][2][r] * acc[mf][2][r] + acc[mf][3][r] * acc[mf][3][r];
            }
        #pragma unroll
        for (int m = 1; m < 16; m <<= 1)
            #pragma unroll
            for (int mf = 0; mf < 4; ++mf)
                #pragma unroll
                for (int r = 0; r < 4; ++r) {
                    ss0[mf][r] += __shfl_xor(ss0[mf][r], m);
                    ss1[mf][r] += __shfl_xor(ss1[mf][r], m);
                }
        ushort* dst = (round == 0) ? q_ws : k_ws;
        #pragma unroll
        for (int mf = 0; mf < 4; ++mf)
            #pragma unroll
            for (int r = 0; r < 4; ++r) {
                float rs0 = 1.0f / (sqrtf(ss0[mf][r]) + 1e-12f);
                float rs1 = 1.0f / (sqrtf(ss1[mf][r]) + 1e-12f);
                size_t rowoff = ((size_t)lwin * 64 + mf * 16 + lg * 4 + r) * 256;
                #pragma unroll
                for (int nf = 0; nf < 4; ++nf)
                    dst[rowoff + w * 64 + nf * 16 + lr] =
                        f2b(acc[mf][nf][r] * (nf < 2 ? rs0 : rs1));
            }
    } else {
        #pragma unroll
        for (int nf = 0; nf < 4; ++nf) {
            int h = 2 * w + (nf >> 1);
            int chan = (nf & 1) * 16 + lr;
            ushort* vrow = vT_ws + (((size_t)lwin * 8 + h) * 32 + chan) * 64;
            #pragma unroll
            for (int mf = 0; mf < 4; ++mf)
                #pragma unroll
                for (int r = 0; r < 4; ++r)
                    vrow[mf * 16 + lg * 4 + r] = f2b(acc[mf][nf][r]);
        }
    }
#undef QK_LA
#undef QK_LB
}

// ---------------- fused attention (S+softmax+PV) + proj + post-LN + residual (bf16 stream) ----------------
__global__ __launch_bounds__(256, 2) void attnproj_kernel(
    const ushort* __restrict__ q_ws, const ushort* __restrict__ k_ws,
    const ushort* __restrict__ vT_ws, const ushort* __restrict__ pwb,
    const float* __restrict__ pb, const float* __restrict__ lsc,
    const float* __restrict__ biasx, const float* __restrict__ n1s,
    const float* __restrict__ n1b, ushort* __restrict__ xb, int shift, int win0)
{
    extern __shared__ ushort sm[];
    ushort* aol  = sm + 4 * 64 * 72;    // [64][256] bf16, swizzled
    float*  outT = (float*)sm;          // [64][264] f32 overlay

    const int t = threadIdx.x;
    const int win = win0 + blockIdx.x, lwin = blockIdx.x;
    const int b = win >> 6, wh = (win >> 3) & 7, ww = win & 7;
    const int w = t >> 6, l = t & 63, lr = l & 15, lg = l >> 4;
    ushort* Pw = sm + w * 64 * 72;      // wave-private P
    const size_t tokbase = (size_t)lwin * 64;
    const f32x4 zf = { 0.f, 0.f, 0.f, 0.f };

    int regc[4], regr[4][4];
    #pragma unroll
    for (int nf = 0; nf < 4; ++nf) {
        int kc = nf * 16 + lr;
        int pr = wh * 8 + (kc >> 3), pc = ww * 8 + (kc & 7);
        regc[nf] = ((pr < 56) ? 0 : ((pr < 60) ? 1 : 2)) * 3 +
                   ((pc < 56) ? 0 : ((pc < 60) ? 1 : 2));
    }
    #pragma unroll
    for (int mf = 0; mf < 4; ++mf)
        #pragma unroll
        for (int r = 0; r < 4; ++r) {
            int n = mf * 16 + lg * 4 + r;
            int pr = wh * 8 + (n >> 3), pc = ww * 8 + (n & 7);
            regr[mf][r] = ((pr < 56) ? 0 : ((pr < 60) ? 1 : 2)) * 3 +
                          ((pc < 56) ? 0 : ((pc < 60) ? 1 : 2));
        }

    for (int hr = 0; hr < 2; ++hr) {
        const int h = w * 2 + hr;

        f32x4 sacc[4][4];
        {
            bf16x8 aq[4], bk[4];
            #pragma unroll
            for (int mf = 0; mf < 4; ++mf)
                aq[mf] = *reinterpret_cast<const bf16x8*>(
                    q_ws + (tokbase + mf * 16 + lr) * 256 + h * 32 + lg * 8);
            #pragma unroll
            for (int nf = 0; nf < 4; ++nf)
                bk[nf] = *reinterpret_cast<const bf16x8*>(
                    k_ws + (tokbase + nf * 16 + lr) * 256 + h * 32 + lg * 8);
            #pragma unroll
            for (int mf = 0; mf < 4; ++mf)
                #pragma unroll
                for (int nf = 0; nf < 4; ++nf)
                    sacc[mf][nf] = MFMA16(aq[mf], bk[nf], zf);
        }

        const float scale = __expf(fminf(lsc[h], 4.6051702f));
        float mx[4][4], sum[4][4];
        #pragma unroll
        for (int mf = 0; mf < 4; ++mf)
            #pragma unroll
            for (int r = 0; r < 4; ++r) mx[mf][r] = -1e30f;

        #pragma unroll
        for (int nf = 0; nf < 4; ++nf)
            #pragma unroll
            for (int mf = 0; mf < 4; ++mf)
                #pragma unroll
                for (int r = 0; r < 4; ++r) {
                    float v = sacc[mf][nf][r] * scale +
                              biasx[((size_t)(h * 64 + mf * 16 + lg * 4 + r)) * 64 + nf * 16 + lr];
                    if (shift && regc[nf] != regr[mf][r]) v -= 100.0f;
                    sacc[mf][nf][r] = v;
                    mx[mf][r] = fmaxf(mx[mf][r], v);
                }
        #pragma unroll
        for (int m = 1; m < 16; m <<= 1)
            #pragma unroll
            for (int mf = 0; mf < 4; ++mf)
                #pragma unroll
                for (int r = 0; r < 4; ++r) mx[mf][r] = fmaxf(mx[mf][r], __shfl_xor(mx[mf][r], m));

        #pragma unroll
        for (int mf = 0; mf < 4; ++mf)
            #pragma unroll
            for (int r = 0; r < 4; ++r) sum[mf][r] = 0.f;
        #pragma unroll
        for (int nf = 0; nf < 4; ++nf)
            #pragma unroll
            for (int mf = 0; mf < 4; ++mf)
                #pragma unroll
                for (int r = 0; r < 4; ++r) {
                    float e = __expf(sacc[mf][nf][r] - mx[mf][r]);
                    sacc[mf][nf][r] = e;
                    sum[mf][r] += e;
                }
        #pragma unroll
        for (int m = 1; m < 16; m <<= 1)
            #pragma unroll
            for (int mf = 0; mf < 4; ++mf)
                #pragma unroll
                for (int r = 0; r < 4; ++r) sum[mf][r] += __shfl_xor(sum[mf][r], m);

        #pragma unroll
        for (int nf = 0; nf < 4; ++nf)
            #pragma unroll
            for (int mf = 0; mf < 4; ++mf)
                #pragma unroll
                for (int r = 0; r < 4; ++r)
                    Pw[(mf * 16 + lg * 4 + r) * 72 + nf * 16 + lr] = f2b(sacc[mf][nf][r]);

        f32x4 oacc[4][2];
        #pragma unroll
        for (int mf = 0; mf < 4; ++mf)
            #pragma unroll
            for (int nf = 0; nf < 2; ++nf) oacc[mf][nf] = zf;
        #pragma unroll
        for (int ks = 0; ks < 2; ++ks) {
            bf16x8 pa[4], bv[2];
            #pragma unroll
            for (int mf = 0; mf < 4; ++mf)
                pa[mf] = *reinterpret_cast<const bf16x8*>(Pw + (mf * 16 + lr) * 72 + ks * 32 + lg * 8);
            #pragma unroll
            for (int nf = 0; nf < 2; ++nf)
                bv[nf] = *reinterpret_cast<const bf16x8*>(
                    vT_ws + (((size_t)lwin * 8 + h) * 32 + nf * 16 + lr) * 64 + ks * 32 + lg * 8);
            #pragma unroll
            for (int mf = 0; mf < 4; ++mf)
                #pragma unroll
                for (int nf = 0; nf < 2; ++nf)
                    oacc[mf][nf] = MFMA16(pa[mf], bv[nf], oacc[mf][nf]);
        }

        #pragma unroll
        for (int mf = 0; mf < 4; ++mf)
            #pragma unroll
            for (int r = 0; r < 4; ++r) {
                float inv = 1.0f / sum[mf][r];
                int row = mf * 16 + lg * 4 + r;
                #pragma unroll
                for (int nf = 0; nf < 2; ++nf) {
                    int col = h * 32 + nf * 16 + lr;
                    aol[row * 256 + (col ^ ((row & 7) << 3))] = f2b(oacc[mf][nf][r] * inv);
                }
            }
    }
    __syncthreads();

    // ---- proj GEMM: M=64, N=64 (wave slice), K=256, prefetched ----
    const int aswz = (lr & 7) << 3;
#define PJ_LA(D, KT) { int k0_ = (KT) * 32 + lg * 8;                                          \
    _Pragma("unroll") for (int mf_ = 0; mf_ < 4; ++mf_)                                       \
        D[mf_] = *reinterpret_cast<const bf16x8*>(aol + (mf_ * 16 + lr) * 256 + (k0_ ^ aswz)); }
#define PJ_LB(D, KT) { int k0_ = (KT) * 32 + lg * 8;                                          \
    _Pragma("unroll") for (int nf_ = 0; nf_ < 4; ++nf_)                                       \
        D[nf_] = *reinterpret_cast<const bf16x8*>(pwb + (size_t)(w * 64 + nf_ * 16 + lr) * 256 + k0_); }

    f32x4 acc[4][4];
    #pragma unroll
    for (int mf = 0; mf < 4; ++mf)
        #pragma unroll
        for (int nf = 0; nf < 4; ++nf) acc[mf][nf] = zf;
    {
        bf16x8 pa0[4], pb0[4], pa1[4], pb1[4];
        PJ_LA(pa0, 0); PJ_LB(pb0, 0);
        #pragma unroll
        for (int kt = 0; kt < 8; kt += 2) {
            PJ_LA(pa1, kt + 1); PJ_LB(pb1, kt + 1);
            TILE_MFMA(acc, pa0, pb0);
            if (kt + 2 < 8) { PJ_LA(pa0, kt + 2); PJ_LB(pb0, kt + 2); }
            TILE_MFMA(acc, pa1, pb1);
        }
    }
#undef PJ_LA
#undef PJ_LB
    __syncthreads();

    #pragma unroll
    for (int nf = 0; nf < 4; ++nf) {
        int c = w * 64 + nf * 16 + lr;
        float bb = pb[c];
        #pragma unroll
        for (int mf = 0; mf < 4; ++mf)
            #pragma unroll
            for (int r = 0; r < 4; ++r)
                outT[(mf * 16 + lg * 4 + r) * 264 + c] = acc[mf][nf][r] + bb;
    }
    __syncthreads();

    for (int u = 0; u < 16; ++u) {
        int tk = w * 16 + u;
        float v0 = outT[tk * 264 + l];
        float v1 = outT[tk * 264 + l + 64];
        float v2 = outT[tk * 264 + l + 128];
        float v3 = outT[tk * 264 + l + 192];
        float s = v0 + v1 + v2 + v3, ss = v0 * v0 + v1 * v1 + v2 * v2 + v3 * v3;
        for (int m = 1; m < 64; m <<= 1) { s += __shfl_xor(s, m); ss += __shfl_xor(ss, m); }
        float mean = s * (1.0f / 256.0f);
        float var  = ss * (1.0f / 256.0f) - mean * mean;
        float rs   = rsqrtf(var + 1e-5f);

        int i = tk >> 3, j = tk & 7;
        int pr = (wh * 8 + i + shift) & 63;
        int pc = (ww * 8 + j + shift) & 63;
        size_t gaddr = ((size_t)(b * 4096 + pr * 64 + pc)) * 256;
        float o0 = b2f(xb[gaddr + l])       + (v0 - mean) * rs * n1s[l]       + n1b[l];
        float o1 = b2f(xb[gaddr + l + 64])  + (v1 - mean) * rs * n1s[l + 64]  + n1b[l + 64];
        float o2 = b2f(xb[gaddr + l + 128]) + (v2 - mean) * rs * n1s[l + 128] + n1b[l + 128];
        float o3 = b2f(xb[gaddr + l + 192]) + (v3 - mean) * rs * n1s[l + 192] + n1b[l + 192];
        xb[gaddr + l]       = f2b(o0);
        xb[gaddr + l + 64]  = f2b(o1);
        xb[gaddr + l + 128] = f2b(o2);
        xb[gaddr + l + 192] = f2b(o3);
    }
}

// ---------------- MLP GEMM1: hid = fast_gelu(xb @ w1^T + b1) -> hidb (bf16, chunk-local) ----------------
__global__ __launch_bounds__(256, 2) void mlp1_kernel(
    const ushort* __restrict__ xb, const ushort* __restrict__ w1b,
    const float* __restrict__ b1, ushort* __restrict__ hidb, int tok_base)
{
    __shared__ ushort xs[64 * 256];      // 32 KB
    __shared__ ushort hstage[64 * 256];  // 32 KB
    const int t = threadIdx.x;
    const size_t ltok0 = (size_t)blockIdx.x * 64;
    const size_t tok0  = (size_t)tok_base + ltok0;
    const int w = t >> 6, l = t & 63, lr = l & 15, lg = l >> 4;
    const int aswz = (lr & 7) << 3;
    const f32x4 zf = { 0.f, 0.f, 0.f, 0.f };

    {   // stage x tile: pure bf16 copy, swizzled
        int row = t >> 2, seg = t & 3;
        const ushort* src = xb + (tok0 + row) * 256 + seg * 64;
        #pragma unroll
        for (int k8 = 0; k8 < 8; ++k8) {
            bf16x8 v = *reinterpret_cast<const bf16x8*>(src + k8 * 8);
            int col = seg * 64 + k8 * 8;
            *reinterpret_cast<bf16x8*>(xs + row * 256 + (col ^ ((row & 7) << 3))) = v;
        }
    }
    __syncthreads();

#define M1_LA(D, KT) { int k0_ = (KT) * 32 + lg * 8;                                        \
    _Pragma("unroll") for (int mf_ = 0; mf_ < 4; ++mf_)                                     \
        D[mf_] = *reinterpret_cast<const bf16x8*>(xs + (mf_ * 16 + lr) * 256 + (k0_ ^ aswz)); }
#define M1_LB(D, KT) { int k0_ = (KT) * 32 + lg * 8;                                        \
    _Pragma("unroll") for (int nf_ = 0; nf_ < 4; ++nf_)                                     \
        D[nf_] = *reinterpret_cast<const bf16x8*>(w1b + (size_t)(n0 + nf_ * 16 + lr) * 256 + k0_); }

    for (int q = 0; q < 4; ++q) {
        const int n0 = q * 256 + w * 64;
        f32x4 acc[4][4];
        #pragma unroll
        for (int mf = 0; mf < 4; ++mf)
            #pragma unroll
            for (int nf = 0; nf < 4; ++nf) acc[mf][nf] = zf;

        bf16x8 pb[3][4];
        M1_LB(pb[0], 0); M1_LB(pb[1], 1);
        #pragma unroll
        for (int kt = 0; kt < 8; ++kt) {
            if (kt + 2 < 8) M1_LB(pb[(kt + 2) % 3], kt + 2);
            bf16x8 pa[4];
            M1_LA(pa, kt);
            TILE_MFMA(acc, pa, pb[kt % 3]);
        }

        if (q > 0) __syncthreads();

        #pragma unroll
        for (int nf = 0; nf < 4; ++nf) {
            int lcol = w * 64 + nf * 16 + lr;
            float bb = b1[q * 256 + lcol];
            #pragma unroll
            for (int mf = 0; mf < 4; ++mf)
                #pragma unroll
                for (int r = 0; r < 4; ++r)
                    hstage[(mf * 16 + lg * 4 + r) * 256 + lcol] =
                        f2b(fast_gelu(acc[mf][nf][r] + bb));
        }
        __syncthreads();

        #pragma unroll
        for (int j = 0; j < 8; ++j) {
            int c = j * 256 + t;
            int row = c >> 5, cc = (c & 31) * 8;
            *reinterpret_cast<bf16x8*>(hidb + (ltok0 + row) * 1024 + q * 256 + cc) =
                *reinterpret_cast<const bf16x8*>(hstage + row * 256 + cc);
        }
    }
#undef M1_LA
#undef M1_LB
}

// ---------------- MLP GEMM2 (LDS-staged dbuf): out = hid @ w2^T + b2, post-LN, residual ----------------
// residual from bf16 xb; writes xb (non-final) or f32 x=d_out (final layer)
__global__ __launch_bounds__(256, 2) void mlp2_kernel(
    const ushort* __restrict__ hidb, const ushort* __restrict__ w2b,
    const float* __restrict__ b2, const float* __restrict__ n2s,
    const float* __restrict__ n2b, float* __restrict__ x,
    ushort* __restrict__ xb, int tok_base, int last)
{
    extern __shared__ ushort sm3[];
    ushort* As = sm3;                   // [2][64][64]
    ushort* Bs = sm3 + 2 * 64 * 64;     // [2][4][64][64]
    float*  outT = (float*)sm3;         // [64][264] overlay (epilogue)

    const int t = threadIdx.x;
    const size_t ltok0 = (size_t)blockIdx.x * 64;
    const size_t tok0  = (size_t)tok_base + ltok0;
    const int w = t >> 6, l = t & 63, lr = l & 15, lg = l >> 4;
    const f32x4 zf = { 0.f, 0.f, 0.f, 0.f };

    const int arow = t >> 2, aslot0 = (t & 3) * 2;
    const ushort* agp = hidb + (ltok0 + arow) * 1024;
    const ushort* bgp = w2b + (size_t)(w * 64 + l) * 1024;

    bf16x8 areg[2], breg[8];
    #pragma unroll
    for (int i = 0; i < 2; ++i)
        areg[i] = *reinterpret_cast<const bf16x8*>(agp + (aslot0 + i) * 8);
    #pragma unroll
    for (int s = 0; s < 8; ++s)
        breg[s] = *reinterpret_cast<const bf16x8*>(bgp + s * 8);
    {
        ushort* aw = As + arow * 64;
        ushort* bw = Bs + (size_t)(w * 64 + l) * 64;
        #pragma unroll
        for (int i = 0; i < 2; ++i)
            *reinterpret_cast<bf16x8*>(aw + (((aslot0 + i) ^ (arow & 7)) * 8)) = areg[i];
        #pragma unroll
        for (int s = 0; s < 8; ++s)
            *reinterpret_cast<bf16x8*>(bw + ((s ^ (l & 7)) * 8)) = breg[s];
    }

    f32x4 acc[4][4];
    #pragma unroll
    for (int mf = 0; mf < 4; ++mf)
        #pragma unroll
        for (int nf = 0; nf < 4; ++nf) acc[mf][nf] = zf;

    for (int kt = 0; kt < 16; ++kt) {
        const int cur = kt & 1, nxt = cur ^ 1;
        if (kt + 1 < 16) {
            #pragma unroll
            for (int i = 0; i < 2; ++i)
                areg[i] = *reinterpret_cast<const bf16x8*>(agp + (kt + 1) * 64 + (aslot0 + i) * 8);
            #pragma unroll
            for (int s = 0; s < 8; ++s)
                breg[s] = *reinterpret_cast<const bf16x8*>(bgp + (kt + 1) * 64 + s * 8);
        }
        __syncthreads();

        const ushort* ar = As + cur * 64 * 64;
        const ushort* br = Bs + (size_t)(cur * 4 + w) * 64 * 64;
        #pragma unroll
        for (int k2 = 0; k2 < 2; ++k2) {
            bf16x8 a[4], b[4];
            #pragma unroll
            for (int mf = 0; mf < 4; ++mf)
                a[mf] = *reinterpret_cast<const bf16x8*>(
                    ar + (mf * 16 + lr) * 64 + (((k2 * 4 + lg) ^ (lr & 7)) * 8));
            #pragma unroll
            for (int nf = 0; nf < 4; ++nf)
                b[nf] = *reinterpret_cast<const bf16x8*>(
                    br + (nf * 16 + lr) * 64 + (((k2 * 4 + lg) ^ (lr & 7)) * 8));
            TILE_MFMA(acc, a, b);
        }
        __syncthreads();

        if (kt + 1 < 16) {
            ushort* aw = As + nxt * 64 * 64 + arow * 64;
            ushort* bw = Bs + (size_t)(nxt * 4 + w) * 64 * 64 + (size_t)l * 64;
            #pragma unroll
            for (int i = 0; i < 2; ++i)
                *reinterpret_cast<bf16x8*>(aw + (((aslot0 + i) ^ (arow & 7)) * 8)) = areg[i];
            #pragma unroll
            for (int s = 0; s < 8; ++s)
                *reinterpret_cast<bf16x8*>(bw + ((s ^ (l & 7)) * 8)) = breg[s];
        }
    }
    __syncthreads();

    #pragma unroll
    for (int nf = 0; nf < 4; ++nf) {
        int c = w * 64 + nf * 16 + lr;
        float bb = b2[c];
        #pragma unroll
        for (int mf = 0; mf < 4; ++mf)
            #pragma unroll
            for (int r = 0; r < 4; ++r)
                outT[(mf * 16 + lg * 4 + r) * 264 + c] = acc[mf][nf][r] + bb;
    }
    __syncthreads();

    for (int u = 0; u < 16; ++u) {
        int tk = w * 16 + u;
        float v0 = outT[tk * 264 + l];
        float v1 = outT[tk * 264 + l + 64];
        float v2 = outT[tk * 264 + l + 128];
        float v3 = outT[tk * 264 + l + 192];
        float s = v0 + v1 + v2 + v3, ss = v0 * v0 + v1 * v1 + v2 * v2 + v3 * v3;
        for (int m = 1; m < 64; m <<= 1) { s += __shfl_xor(s, m); ss += __shfl_xor(ss, m); }
        float mean = s * (1.0f / 256.0f);
        float var  = ss * (1.0f / 256.0f) - mean * mean;
        float rs   = rsqrtf(var + 1e-5f);
        ushort* xbp = xb + (tok0 + tk) * 256;
        float o0 = b2f(xbp[l])       + (v0 - mean) * rs * n2s[l]       + n2b[l];
        float o1 = b2f(xbp[l + 64])  + (v1 - mean) * rs * n2s[l + 64]  + n2b[l + 64];
        float o2 = b2f(xbp[l + 128]) + (v2 - mean) * rs * n2s[l + 128] + n2b[l + 128];
        float o3 = b2f(xbp[l + 192]) + (v3 - mean) * rs * n2s[l + 192] + n2b[l + 192];
        if (last) {
            float* xp = x + (tok0 + tk) * 256;
            xp[l]       = o0;
            xp[l + 64]  = o1;
            xp[l + 128] = o2;
            xp[l + 192] = o3;
        } else {
            xbp[l]       = f2b(o0);
            xbp[l + 64]  = f2b(o1);
            xbp[l + 128] = f2b(o2);
            xbp[l + 192] = f2b(o3);
        }
    }
}

// ---------------- launcher ----------------
extern "C" void kernel_launch(void* const* d_in, const int* in_sizes, int n_in,
                              void* d_out, int out_size, void* d_ws, size_t ws_size,
                              hipStream_t stream) {
    (void)in_sizes; (void)n_in; (void)out_size;
    const float* tokens = (const float*)d_in[0];
    const float* qkv_w  = (const float*)d_in[3];
    const float* qkv_b  = (const float*)d_in[4];
    const float* lsc    = (const float*)d_in[5];
    const float* cw1    = (const float*)d_in[6];
    const float* cb1    = (const float*)d_in[7];
    const float* cw2    = (const float*)d_in[8];
    const float* pw     = (const float*)d_in[9];
    const float* pb     = (const float*)d_in[10];
    const float* n1s    = (const float*)d_in[11];
    const float* n1b    = (const float*)d_in[12];
    const float* mw1    = (const float*)d_in[13];
    const float* mb1    = (const float*)d_in[14];
    const float* mw2    = (const float*)d_in[15];
    const float* mb2    = (const float*)d_in[16];
    const float* n2s    = (const float*)d_in[17];
    const float* n2b    = (const float*)d_in[18];

    float* x = (float*)d_out;

    // ---- workspace: weights | xb (32 MB bf16 residual stream) | q/k/vT (hidb overlays) ----
    ushort* pwb   = (ushort*)d_ws;                       // 256 KB
    ushort* w1b   = pwb + 2 * 256 * 256;                 // 1 MB
    ushort* w2b   = w1b + 2 * 1024 * 256;                // 1 MB
    ushort* qwb   = w2b + 2 * 256 * 1024;                // 768 KB
    float*  biasx = (float*)(qwb + 2 * 768 * 256);       // 128 KB
    float*  biastab = biasx + 8 * 64 * 64;               // 1800 f32
    char*   big   = (char*)d_ws + 3407872;               // 3.25 MB offset

    ushort* xb    = (ushort*)big;                        // NTOK*256 bf16 = 32 MB
    char*   big2  = big + (size_t)NTOK * 256 * 2;

    size_t avail2 = ws_size - 3407872 - (size_t)NTOK * 256 * 2;
    const int hwin = (avail2 >= (size_t)3 * 1024 * 64 * 256 * 2) ? 1024 : 512;
    const int chunk_tok = (avail2 >= (size_t)32768 * 2048) ? 32768 : 16384;

    ushort* q_ws  = (ushort*)big2;
    ushort* k_ws  = q_ws + (size_t)hwin * 64 * 256;
    ushort* vT_ws = k_ws + (size_t)hwin * 64 * 256;
    ushort* hidb  = (ushort*)big2;   // overlay (q/k/vT dead during MLP; xb stays live)

    f2b_kernel<<<dim3(2 * 256 * 256 / 1024),  dim3(256), 0, stream>>>(pwb, pw);
    f2b_kernel<<<dim3(2 * 1024 * 256 / 1024), dim3(256), 0, stream>>>(w1b, mw1);
    f2b_kernel<<<dim3(2 * 256 * 1024 / 1024), dim3(256), 0, stream>>>(w2b, mw2);
    f2b_kernel<<<dim3(2 * 768 * 256 / 1024),  dim3(256), 0, stream>>>(qwb, qkv_w);
    f2b_kernel<<<dim3(NTOK * 256 / 1024),     dim3(256), 0, stream>>>(xb, tokens);  // stream init

    for (int l = 0; l < 2; ++l) {
        const int shift = l ? 4 : 0;
        cpb_kernel<<<dim3(225), dim3(256), 0, stream>>>(
            cw1 + (size_t)l * 1024, cb1 + (size_t)l * 512, cw2 + (size_t)l * 4096, biastab);
        biasx_kernel<<<dim3(512), dim3(64), 0, stream>>>(biastab, biasx);
        for (int win0 = 0; win0 < 1024; win0 += hwin) {
            qkv_kernel<<<dim3(3, hwin), dim3(256), 0, stream>>>(
                xb, qwb + (size_t)l * 196608, qkv_b + (size_t)l * 768,
                q_ws, k_ws, vT_ws, shift, win0);
            attnproj_kernel<<<dim3(hwin), dim3(256), AP_LDS, stream>>>(
                q_ws, k_ws, vT_ws, pwb + (size_t)l * 65536, pb + (size_t)l * 256,
                lsc + (size_t)l * 8, biasx, n1s + (size_t)l * 256, n1b + (size_t)l * 256,
                xb, shift, win0);
        }
        for (int tb = 0; tb < NTOK; tb += chunk_tok) {
            mlp1_kernel<<<dim3(chunk_tok / 64), dim3(256), 0, stream>>>(
                xb, w1b + (size_t)l * 262144, mb1 + (size_t)l * 1024, hidb, tb);
            mlp2_kernel<<<dim3(chunk_tok / 64), dim3(256), MLP2_LDS, stream>>>(
                hidb, w2b + (size_t)l * 262144, mb2 + (size_t)l * 256,
                n2s + (size_t)l * 256, n2b + (size_t)l * 256, x, xb, tb, l == 1 ? 1 : 0);
        }
    }
}